// Round 8
// baseline (1484.510 us; speedup 1.0000x reference)
//
#include <hip/hip_runtime.h>
#include <math.h>

#define NPTS 8192
#define KNN 20
#define CAP 256

static __device__ __forceinline__ unsigned long long umin64(unsigned long long a, unsigned long long b) {
    return a < b ? a : b;
}

// ---------------- row squared norms: bit-faithful replica of np.sum(x*x, -1) ----------------
template<int C>
__global__ void rowsq_np_kernel(const float* __restrict__ X, int ld, float* __restrict__ x2) {
#pragma clang fp contract(off)
    int i = blockIdx.x * blockDim.x + threadIdx.x;
    if (i >= NPTS) return;
    const float* row = X + (long)i * ld;
    float res;
    if (C < 8) {
        res = 0.f;
        for (int c = 0; c < C; ++c) res += row[c] * row[c];
    } else {
        float r[8];
#pragma unroll
        for (int j = 0; j < 8; ++j) r[j] = row[j] * row[j];
        int p = 8;
        for (; p < C - (C % 8); p += 8)
#pragma unroll
            for (int j = 0; j < 8; ++j) r[j] += row[p + j] * row[p + j];
        res = ((r[0] + r[1]) + (r[2] + r[3])) + ((r[4] + r[5]) + (r[6] + r[7]));
        for (; p < C; ++p) res += row[p] * row[p];
    }
    x2[i] = res;
}

// ---------------- block-wide count of keys <= B (conflict-free, no atomics) ----------------
// scal[0..3] used as wave partials. Returns total in all threads.
__device__ __forceinline__ int block_count_le(const unsigned* keys, unsigned B, int* scal) {
    const int tid = threadIdx.x;
    int cnt = 0;
    for (int m = 0; m < NPTS / 256; ++m)
        cnt += (keys[tid + 256 * m] <= B) ? 1 : 0;
#pragma unroll
    for (int o = 32; o >= 1; o >>= 1) cnt += __shfl_down(cnt, (unsigned)o);
    if ((tid & 63) == 0) scal[tid >> 6] = cnt;
    __syncthreads();
    int tot = scal[0] + scal[1] + scal[2] + scal[3];
    __syncthreads();   // scal reusable after this
    return tot;
}

// ---------------- exact top-K via sample-quantile threshold (ascending by (key,index)) ----------------
// No LDS-atomic histograms: threshold B found from order statistics of 256 samples;
// any B with count(keys<=B) in [KNN, CAP] yields the exact stable top-K after
// candidate collection + exact (key,idx) extraction. Fallback: exact 20-round scan.
__device__ __forceinline__ void sample_select20(unsigned* keys, unsigned* samp,
                                                unsigned long long* cand, int* scal,
                                                long row, int* __restrict__ idx_out) {
    const int tid = threadIdx.x;
    // 256 distinct samples, bank-spread: j = 1024*(tid/32) + 33*(tid%32)
    unsigned s = keys[(tid << 5) | (tid & 31)];
    samp[tid] = s;
    __syncthreads();
    int r = 0;
    for (int k = 0; k < 256; ++k) {
        unsigned v = samp[k];                      // broadcast read
        r += (int)((v < s) || (v == s && k < tid));
    }
    __syncthreads();
    samp[r] = s;                                   // samp now sorted ascending
    __syncthreads();

    // smallest sample rank with count >= KNN (count(samp[255]) >= 256 >= KNN always)
    int lo = 0, hi = 255;
    while (lo < hi) {
        int mid = (lo + hi) >> 1;
        int c = block_count_le(keys, samp[mid], scal);
        if (c >= KNN) hi = mid; else lo = mid + 1;
    }
    const unsigned B = samp[lo];
    const int c = block_count_le(keys, B, scal);
    if (tid == 0) scal[4] = 0;
    __syncthreads();

    if (c <= CAP) {
        for (int m = 0; m < NPTS / 256; ++m) {
            int j = tid + 256 * m;
            unsigned u = keys[j];
            if (u <= B) {
                int p = atomicAdd(&scal[4], 1);    // ~c ops total, negligible
                cand[p] = (((unsigned long long)u) << 32) | (unsigned)j;
            }
        }
        __syncthreads();
        const int nc = scal[4];
        if (tid < 64) {
            unsigned long long cc[4];
#pragma unroll
            for (int q = 0; q < 4; ++q) { int i = tid + 64 * q; cc[q] = (i < nc) ? cand[i] : ~0ull; }
            for (int it = 0; it < KNN; ++it) {
                unsigned long long g = umin64(umin64(cc[0], cc[1]), umin64(cc[2], cc[3]));
#pragma unroll
                for (int o = 1; o < 64; o <<= 1) g = umin64(g, __shfl_xor(g, o));
                if (tid == 0) idx_out[row * KNN + it] = (int)(unsigned)(g & 0xFFFFFFFFull);
#pragma unroll
                for (int q = 0; q < 4; ++q) if (cc[q] == g) cc[q] = ~0ull;
            }
        }
    } else {
        // exact fallback (massive ties) — not expected on this data; cand[0..3] as partials
        for (int it = 0; it < KNN; ++it) {
            unsigned long long best = ~0ull;
            for (int m = 0; m < NPTS / 256; ++m) {
                int j = tid + 256 * m;
                best = umin64(best, (((unsigned long long)keys[j]) << 32) | (unsigned)j);
            }
#pragma unroll
            for (int o = 1; o < 64; o <<= 1) best = umin64(best, __shfl_xor(best, o));
            if ((tid & 63) == 0) cand[tid >> 6] = best;
            __syncthreads();
            unsigned long long g = umin64(umin64(cand[0], cand[1]), umin64(cand[2], cand[3]));
            int j = (int)(unsigned)(g & 0xFFFFFFFFull);
            if (tid == 0) idx_out[row * KNN + it] = j;
            __syncthreads();
            if (tid == (j & 255)) keys[j] = 0xFFFFFFFFu;
            __syncthreads();
        }
    }
}

// ---------------- stage-1 fused: C=3 distances + top-K, no dist materialization ----------------
__global__ __launch_bounds__(256) void knn3_fused_kernel(const float* __restrict__ X,
                                                         const float* __restrict__ x2,
                                                         int* __restrict__ idx_out) {
    __shared__ unsigned int keys[NPTS];
    __shared__ unsigned int samp[256];
    __shared__ unsigned long long cand[CAP];
    __shared__ int scal[8];
    const int tid = threadIdx.x;
    const int row = blockIdx.x;
    const float xi0 = X[(long)row * 3], xi1 = X[(long)row * 3 + 1], xi2 = X[(long)row * 3 + 2];
    const float x2i = x2[row];

    for (int m = 0; m < NPTS / 256; ++m) {
        int j = tid + 256 * m;
        float accv = 0.f;
        accv = fmaf(xi0, X[(long)j * 3], accv);
        accv = fmaf(xi1, X[(long)j * 3 + 1], accv);
        accv = fmaf(xi2, X[(long)j * 3 + 2], accv);
        float d = (x2i + x2[j]) - 2.f * accv;
        unsigned u = __float_as_uint(d);
        keys[j] = (u & 0x80000000u) ? ~u : (u | 0x80000000u);
    }
    __syncthreads();
    sample_select20(keys, samp, cand, scal, row, idx_out);
}

// ---------------- pairwise distance (fp32), 128x128 tile, 8x8 microtile, BK=16 prefetch ----------------
__global__ __launch_bounds__(256) void dist128_kernel(const float* __restrict__ X, int ld, int C,
                                                      const float* __restrict__ x2,
                                                      float* __restrict__ dist, int i0base) {
    __shared__ float As[16][132];
    __shared__ float Bs[16][132];
    const int tid = threadIdx.x;
    const int i0 = i0base + blockIdx.y * 128;
    const int j0 = blockIdx.x * 128;
    const int ty = tid >> 4, tx = tid & 15;
    const int lc = tid & 15, lr = tid >> 4;

    float ra[8], rb[8];
    float acc[8][8];
#pragma unroll
    for (int a = 0; a < 8; ++a)
#pragma unroll
        for (int b = 0; b < 8; ++b) acc[a][b] = 0.f;

    {
        const bool v = (lc < C);
#pragma unroll
        for (int q = 0; q < 8; ++q) {
            int r = lr + 16 * q;
            ra[q] = v ? X[(long)(i0 + r) * ld + lc] : 0.f;
            rb[q] = v ? X[(long)(j0 + r) * ld + lc] : 0.f;
        }
    }

    for (int k0 = 0; k0 < C; k0 += 16) {
#pragma unroll
        for (int q = 0; q < 8; ++q) {
            As[lc][lr + 16 * q] = ra[q];
            Bs[lc][lr + 16 * q] = rb[q];
        }
        __syncthreads();
        if (k0 + 16 < C) {
            const bool v = (k0 + 16 + lc < C);
#pragma unroll
            for (int q = 0; q < 8; ++q) {
                int r = lr + 16 * q;
                ra[q] = v ? X[(long)(i0 + r) * ld + k0 + 16 + lc] : 0.f;
                rb[q] = v ? X[(long)(j0 + r) * ld + k0 + 16 + lc] : 0.f;
            }
        }
#pragma unroll
        for (int kk = 0; kk < 16; ++kk) {
            float4 a0 = *(const float4*)&As[kk][ty * 8];
            float4 a1 = *(const float4*)&As[kk][ty * 8 + 4];
            float4 b0 = *(const float4*)&Bs[kk][tx * 8];
            float4 b1 = *(const float4*)&Bs[kk][tx * 8 + 4];
            float av[8] = {a0.x, a0.y, a0.z, a0.w, a1.x, a1.y, a1.z, a1.w};
            float bv[8] = {b0.x, b0.y, b0.z, b0.w, b1.x, b1.y, b1.z, b1.w};
#pragma unroll
            for (int ii = 0; ii < 8; ++ii)
#pragma unroll
                for (int jj = 0; jj < 8; ++jj)
                    acc[ii][jj] = fmaf(av[ii], bv[jj], acc[ii][jj]);
        }
        __syncthreads();
    }

    float xj[8];
#pragma unroll
    for (int jj = 0; jj < 8; ++jj) xj[jj] = x2[j0 + tx * 8 + jj];
#pragma unroll
    for (int ii = 0; ii < 8; ++ii) {
        int rloc = blockIdx.y * 128 + ty * 8 + ii;
        float xi = x2[i0base + rloc];
        float4 o0, o1;
        o0.x = (xi + xj[0]) - 2.f * acc[ii][0];
        o0.y = (xi + xj[1]) - 2.f * acc[ii][1];
        o0.z = (xi + xj[2]) - 2.f * acc[ii][2];
        o0.w = (xi + xj[3]) - 2.f * acc[ii][3];
        o1.x = (xi + xj[4]) - 2.f * acc[ii][4];
        o1.y = (xi + xj[5]) - 2.f * acc[ii][5];
        o1.z = (xi + xj[6]) - 2.f * acc[ii][6];
        o1.w = (xi + xj[7]) - 2.f * acc[ii][7];
        *(float4*)&dist[(long)rloc * NPTS + j0 + tx * 8] = o0;
        *(float4*)&dist[(long)rloc * NPTS + j0 + tx * 8 + 4] = o1;
    }
}

// ---------------- top-K from materialized dist rows ----------------
__global__ __launch_bounds__(256) void topk_kernel(const float* __restrict__ dist, int* __restrict__ idx_out,
                                                   int rowbase) {
    __shared__ unsigned int keys[NPTS];
    __shared__ unsigned int samp[256];
    __shared__ unsigned long long cand[CAP];
    __shared__ int scal[8];
    const int tid = threadIdx.x;
    const long row = rowbase + blockIdx.x;
    const float* drow = dist + (long)blockIdx.x * NPTS;

    for (int m = 0; m < NPTS / 256; ++m) {
        int j = tid + 256 * m;
        unsigned u = __float_as_uint(drow[j]);
        keys[j] = (u & 0x80000000u) ? ~u : (u | 0x80000000u);
    }
    __syncthreads();
    sample_select20(keys, samp, cand, scal, row, idx_out);
}

// ---------------- erosion edge-conv (fp32, order-free exact) ----------------
template<int F, int C>
__global__ void erode_kernel(const float* __restrict__ X, int ld, const int* __restrict__ idx,
                             const float* __restrict__ w, float* __restrict__ out, int ldo) {
    __shared__ int nidx[KNN];
    __shared__ float neigh[KNN * C];
    const int tid = threadIdx.x;
    const int row = blockIdx.x;
    if (tid < KNN) nidx[tid] = idx[row * KNN + tid];
    __syncthreads();
    for (int t = tid; t < KNN * C; t += blockDim.x) {
        int k = t / C, c = t % C;
        neigh[t] = X[(long)nidx[k] * ld + c];
    }
    __syncthreads();
    if (tid < F * C) {
        int f = tid / C, c = tid % C;
        float m = neigh[c] - w[f * KNN * C + c];
        for (int k = 1; k < KNN; ++k)
            m = fminf(m, neigh[k * C + c] - w[(f * KNN + k) * C + c]);
        out[(long)row * ldo + tid] = m;
    }
}

// ---------------- fp32 GEMM 128x128 (lin1), BK=16 prefetch, bias+ReLU ----------------
template<int RELU>
__global__ __launch_bounds__(256) void gemm128_kernel(const float* __restrict__ A, const float* __restrict__ B,
                                                      const float* __restrict__ bias, float* __restrict__ Cm,
                                                      int K, int N) {
    __shared__ float As[16][132];
    __shared__ float Bs[16][132];
    const int tid = threadIdx.x;
    const int i0 = blockIdx.y * 128, j0 = blockIdx.x * 128;
    const int ty = tid >> 4, tx = tid & 15;
    const int lc = tid & 15, lr = tid >> 4;
    const int lb_n = tid & 127, lb_k = tid >> 7;

    float ra[8], rb[8];
    float acc[8][8];
#pragma unroll
    for (int a = 0; a < 8; ++a)
#pragma unroll
        for (int b = 0; b < 8; ++b) acc[a][b] = 0.f;

    {
        const bool bn = (j0 + lb_n < N);
#pragma unroll
        for (int q = 0; q < 8; ++q) {
            int r = lr + 16 * q;
            ra[q] = (lc < K) ? A[(long)(i0 + r) * K + lc] : 0.f;
            int kk = lb_k + 2 * q;
            rb[q] = (kk < K && bn) ? B[(long)kk * N + j0 + lb_n] : 0.f;
        }
    }

    for (int k0 = 0; k0 < K; k0 += 16) {
#pragma unroll
        for (int q = 0; q < 8; ++q) {
            As[lc][lr + 16 * q] = ra[q];
            Bs[lb_k + 2 * q][lb_n] = rb[q];
        }
        __syncthreads();
        if (k0 + 16 < K) {
            const bool bn = (j0 + lb_n < N);
#pragma unroll
            for (int q = 0; q < 8; ++q) {
                int r = lr + 16 * q;
                ra[q] = (k0 + 16 + lc < K) ? A[(long)(i0 + r) * K + k0 + 16 + lc] : 0.f;
                int kk = k0 + 16 + lb_k + 2 * q;
                rb[q] = (kk < K && bn) ? B[(long)kk * N + j0 + lb_n] : 0.f;
            }
        }
#pragma unroll
        for (int kk = 0; kk < 16; ++kk) {
            float4 a0 = *(const float4*)&As[kk][ty * 8];
            float4 a1 = *(const float4*)&As[kk][ty * 8 + 4];
            float4 b0 = *(const float4*)&Bs[kk][tx * 8];
            float4 b1 = *(const float4*)&Bs[kk][tx * 8 + 4];
            float av[8] = {a0.x, a0.y, a0.z, a0.w, a1.x, a1.y, a1.z, a1.w};
            float bv[8] = {b0.x, b0.y, b0.z, b0.w, b1.x, b1.y, b1.z, b1.w};
#pragma unroll
            for (int ii = 0; ii < 8; ++ii)
#pragma unroll
                for (int jj = 0; jj < 8; ++jj)
                    acc[ii][jj] = fmaf(av[ii], bv[jj], acc[ii][jj]);
        }
        __syncthreads();
    }

#pragma unroll
    for (int ii = 0; ii < 8; ++ii) {
        int i = i0 + ty * 8 + ii;
#pragma unroll
        for (int jj = 0; jj < 8; ++jj) {
            int j = j0 + tx * 8 + jj;
            if (j < N) {
                float v = acc[ii][jj] + bias[j];
                if (RELU) v = fmaxf(v, 0.f);
                Cm[(long)i * N + j] = v;
            }
        }
    }
}

// ---------------- fp32 GEMM 64x64 (layers 2-4), BK=32 prefetch ----------------
template<int RELU>
__global__ __launch_bounds__(256) void gemm_kernel(const float* __restrict__ A, const float* __restrict__ B,
                                                   const float* __restrict__ bias, float* __restrict__ Cm,
                                                   int K, int N) {
    __shared__ float As[32][68];
    __shared__ float Bs[32][68];
    const int tid = threadIdx.x;
    const int i0 = blockIdx.y * 64, j0 = blockIdx.x * 64;
    const int ty = tid >> 4, tx = tid & 15;
    const int la_c = tid & 31, la_r = tid >> 5;
    const int lb_n = tid & 63, lb_k = tid >> 6;

    float ra[8], rb[8];
    float acc[4][4];
#pragma unroll
    for (int a = 0; a < 4; ++a)
#pragma unroll
        for (int b = 0; b < 4; ++b) acc[a][b] = 0.f;

    {
        const bool bn = (j0 + lb_n < N);
#pragma unroll
        for (int q = 0; q < 8; ++q) {
            int r = la_r + 8 * q;
            ra[q] = (la_c < K) ? A[(long)(i0 + r) * K + la_c] : 0.f;
            int kk = lb_k + 4 * q;
            rb[q] = (kk < K && bn) ? B[(long)kk * N + j0 + lb_n] : 0.f;
        }
    }

    for (int k0 = 0; k0 < K; k0 += 32) {
#pragma unroll
        for (int q = 0; q < 8; ++q) {
            As[la_c][la_r + 8 * q] = ra[q];
            Bs[lb_k + 4 * q][lb_n] = rb[q];
        }
        __syncthreads();
        if (k0 + 32 < K) {
            const bool bn = (j0 + lb_n < N);
#pragma unroll
            for (int q = 0; q < 8; ++q) {
                int r = la_r + 8 * q;
                ra[q] = (k0 + 32 + la_c < K) ? A[(long)(i0 + r) * K + k0 + 32 + la_c] : 0.f;
                int kk = k0 + 32 + lb_k + 4 * q;
                rb[q] = (kk < K && bn) ? B[(long)kk * N + j0 + lb_n] : 0.f;
            }
        }
#pragma unroll
        for (int kk = 0; kk < 32; ++kk) {
            float4 a4 = *(const float4*)&As[kk][ty * 4];
            float4 b4 = *(const float4*)&Bs[kk][tx * 4];
            float av[4] = {a4.x, a4.y, a4.z, a4.w};
            float bv[4] = {b4.x, b4.y, b4.z, b4.w};
#pragma unroll
            for (int ii = 0; ii < 4; ++ii)
#pragma unroll
                for (int jj = 0; jj < 4; ++jj)
                    acc[ii][jj] = fmaf(av[ii], bv[jj], acc[ii][jj]);
        }
        __syncthreads();
    }

#pragma unroll
    for (int ii = 0; ii < 4; ++ii) {
        int i = i0 + ty * 4 + ii;
#pragma unroll
        for (int jj = 0; jj < 4; ++jj) {
            int j = j0 + tx * 4 + jj;
            if (j < N) {
                float v = acc[ii][jj] + bias[j];
                if (RELU) v = fmaxf(v, 0.f);
                Cm[(long)i * N + j] = v;
            }
        }
    }
}

// ---------------- log_softmax over 40 cols, wave per row, in place ----------------
__global__ void logsoftmax_kernel(float* __restrict__ out) {
    const int lane = threadIdx.x & 63;
    const int wid = threadIdx.x >> 6;
    const int row = blockIdx.x * 4 + wid;
    float* o = out + (long)row * 40;
    float v = (lane < 40) ? o[lane] : -INFINITY;
    float m = v;
#pragma unroll
    for (int off = 1; off < 64; off <<= 1) m = fmaxf(m, __shfl_xor(m, off));
    float e = (lane < 40) ? expf(v - m) : 0.f;
    float s = e;
#pragma unroll
    for (int off = 1; off < 64; off <<= 1) s += __shfl_xor(s, off);
    float r = (v - m) - logf(s);
    if (lane < 40) o[lane] = r;
}

extern "C" void kernel_launch(void* const* d_in, const int* in_sizes, int n_in,
                              void* d_out, int out_size, void* d_ws, size_t ws_size,
                              hipStream_t stream) {
    (void)in_sizes; (void)n_in; (void)out_size;
    const float* x     = (const float*)d_in[0];
    const float* w1    = (const float*)d_in[1];
    const float* w2    = (const float*)d_in[2];
    const float* w3    = (const float*)d_in[3];
    const float* lin1w = (const float*)d_in[4];
    const float* lin1b = (const float*)d_in[5];
    const float* wa    = (const float*)d_in[6];
    const float* ba    = (const float*)d_in[7];
    const float* wb    = (const float*)d_in[8];
    const float* bb    = (const float*)d_in[9];
    const float* wo    = (const float*)d_in[10];
    const float* bo    = (const float*)d_in[11];
    float* outp = (float*)d_out;

    // ---- ws_size-adaptive layout ----
    char* ws = (char*)d_ws;
    size_t off = 0;
    auto take = [&](size_t bytes) { char* p = ws + off; off += (bytes + 255) & ~(size_t)255; return p; };
    float* x2  = (float*)take((size_t)NPTS * 4);
    int*   idx = (int*)  take((size_t)NPTS * KNN * 4);
    float* h0  = (float*)take((size_t)NPTS * 420 * 4);
    size_t rest = (ws_size > off) ? (ws_size - off) : 0;
    char*  scratch = ws + off;

    int cr = (int)(rest / ((size_t)NPTS * 4));   // fp32 dist chunk rows
    if (cr > 4096) cr = 4096;                    // 128 MB chunk: topk re-read stays L3-resident
    cr &= ~127;
    if (cr < 128) cr = 128;
    float* dist = (float*)scratch;

    int mr = (int)(rest / 5632);                 // fp32 MLP chunk rows
    if (mr > NPTS) mr = NPTS;
    mr &= ~127;
    if (mr < 128) mr = 128;

    dim3 b256(256);
    dim3 grow(NPTS);

    // ---- stage 1: fused knn(x, C=3) -> erode -> x1 = h0[:, 0:60]
    rowsq_np_kernel<3><<<dim3(32), b256, 0, stream>>>(x, 3, x2);
    knn3_fused_kernel<<<grow, b256, 0, stream>>>(x, x2, idx);
    erode_kernel<20, 3><<<grow, dim3(64), 0, stream>>>(x, 3, idx, w1, h0 + 0, 420);

    // ---- stage 2: knn(x1, C=60) -> erode -> x2f = h0[:, 60:180]
    rowsq_np_kernel<60><<<dim3(32), b256, 0, stream>>>(h0, 420, x2);
    for (int r0 = 0; r0 < NPTS; r0 += cr) {
        int rows = (NPTS - r0 < cr) ? (NPTS - r0) : cr;
        dist128_kernel<<<dim3(64, rows / 128), b256, 0, stream>>>(h0, 420, 60, x2, dist, r0);
        topk_kernel<<<dim3(rows), b256, 0, stream>>>(dist, idx, r0);
    }
    erode_kernel<2, 60><<<grow, dim3(128), 0, stream>>>(h0, 420, idx, w2, h0 + 60, 420);

    // ---- stage 3: knn(x2f, C=120) -> erode -> x3 = h0[:, 180:420]
    rowsq_np_kernel<120><<<dim3(32), b256, 0, stream>>>(h0 + 60, 420, x2);
    for (int r0 = 0; r0 < NPTS; r0 += cr) {
        int rows = (NPTS - r0 < cr) ? (NPTS - r0) : cr;
        dist128_kernel<<<dim3(64, rows / 128), b256, 0, stream>>>(h0 + 60, 420, 120, x2, dist, r0);
        topk_kernel<<<dim3(rows), b256, 0, stream>>>(dist, idx, r0);
    }
    erode_kernel<2, 120><<<grow, dim3(256), 0, stream>>>(h0 + 60, 420, idx, w3, h0 + 180, 420);

    // ---- MLP (row-chunked; h1|h2|h3 live in scratch)
    for (int r0 = 0; r0 < NPTS; r0 += mr) {
        int rows = (NPTS - r0 < mr) ? (NPTS - r0) : mr;
        float* h1c = (float*)scratch;
        float* h2c = h1c + (size_t)mr * 1024;
        float* h3c = h2c + (size_t)mr * 256;
        gemm128_kernel<1><<<dim3(8, rows / 128), b256, 0, stream>>>(h0 + (long)r0 * 420, lin1w, lin1b, h1c, 420, 1024);
        gemm_kernel<1><<<dim3(4, rows / 64), b256, 0, stream>>>(h1c, wa, ba, h2c, 1024, 256);
        gemm_kernel<1><<<dim3(2, rows / 64), b256, 0, stream>>>(h2c, wb, bb, h3c, 256, 128);
        gemm_kernel<0><<<dim3(1, rows / 64), b256, 0, stream>>>(h3c, wo, bo, outp + (long)r0 * 40, 128, 40);
        logsoftmax_kernel<<<dim3(rows / 4), b256, 0, stream>>>(outp + (long)r0 * 40);
    }
}

// Round 9
// 1127.131 us; speedup vs baseline: 1.3171x; 1.3171x over previous
//
#include <hip/hip_runtime.h>
#include <math.h>

#define NPTS 8192
#define KNN 20
#define CAP 256

static __device__ __forceinline__ unsigned long long umin64(unsigned long long a, unsigned long long b) {
    return a < b ? a : b;
}
static __device__ __forceinline__ unsigned umin32(unsigned a, unsigned b) { return a < b ? a : b; }

// ---------------- row squared norms: bit-faithful replica of np.sum(x*x, -1) ----------------
template<int C>
__global__ void rowsq_np_kernel(const float* __restrict__ X, int ld, float* __restrict__ x2) {
#pragma clang fp contract(off)
    int i = blockIdx.x * blockDim.x + threadIdx.x;
    if (i >= NPTS) return;
    const float* row = X + (long)i * ld;
    float res;
    if (C < 8) {
        res = 0.f;
        for (int c = 0; c < C; ++c) res += row[c] * row[c];
    } else {
        float r[8];
#pragma unroll
        for (int j = 0; j < 8; ++j) r[j] = row[j] * row[j];
        int p = 8;
        for (; p < C - (C % 8); p += 8)
#pragma unroll
            for (int j = 0; j < 8; ++j) r[j] += row[p + j] * row[p + j];
        res = ((r[0] + r[1]) + (r[2] + r[3])) + ((r[4] + r[5]) + (r[6] + r[7]));
        for (; p < C; ++p) res += row[p] * row[p];
    }
    x2[i] = res;
}

// ---------------- block-wide count of keys <= B (conflict-free, no atomics) ----------------
__device__ __forceinline__ int block_count_le(const unsigned* keys, unsigned B, int* scal) {
    const int tid = threadIdx.x;
    int cnt = 0;
    for (int m = 0; m < NPTS / 256; ++m)
        cnt += (keys[tid + 256 * m] <= B) ? 1 : 0;
#pragma unroll
    for (int o = 32; o >= 1; o >>= 1) cnt += __shfl_down(cnt, (unsigned)o);
    if ((tid & 63) == 0) scal[tid >> 6] = cnt;
    __syncthreads();
    int tot = scal[0] + scal[1] + scal[2] + scal[3];
    __syncthreads();   // scal reusable after this
    return tot;
}

// ---------------- exact top-K via min-scan sample threshold (ascending by (key,index)) ----------------
// Threshold B = smallest active-sample with count(keys<=B) >= KNN, found by repeated
// min-of-samples + one count pass (expected ~1.7 iterations; E[count(min sample)] ~ 32).
// Any B with count in [KNN, CAP] gives the exact stable top-K after candidate
// collection + exact (key,idx) extraction. count > CAP -> exact fallback.
__device__ __forceinline__ void sample_select20(unsigned* keys, unsigned* ured,
                                                unsigned long long* cand, int* scal,
                                                long row, int* __restrict__ idx_out) {
    const int tid = threadIdx.x;
    // one sample per thread, bank-spread unique positions
    unsigned s = keys[(tid << 5) | (tid & 31)];
    unsigned B;
    int c;
    for (;;) {
        unsigned m = s;
#pragma unroll
        for (int o = 32; o >= 1; o >>= 1) m = umin32(m, __shfl_down(m, (unsigned)o));
        if ((tid & 63) == 0) ured[tid >> 6] = m;
        __syncthreads();
        B = umin32(umin32(ured[0], ured[1]), umin32(ured[2], ured[3]));
        __syncthreads();   // ured consumed before next write
        c = block_count_le(keys, B, scal);
        if (c >= KNN) break;
        if (s <= B) s = 0xFFFFFFFFu;   // deactivate exhausted samples (>=1 per iter)
    }
    if (tid == 0) scal[4] = 0;
    __syncthreads();

    if (c <= CAP) {
        for (int m = 0; m < NPTS / 256; ++m) {
            int j = tid + 256 * m;
            unsigned u = keys[j];
            if (u <= B) {
                int p = atomicAdd(&scal[4], 1);    // ~c ops total, negligible
                cand[p] = (((unsigned long long)u) << 32) | (unsigned)j;
            }
        }
        __syncthreads();
        const int nc = scal[4];
        if (tid < 64) {
            unsigned long long cc[4];
#pragma unroll
            for (int q = 0; q < 4; ++q) { int i = tid + 64 * q; cc[q] = (i < nc) ? cand[i] : ~0ull; }
            for (int it = 0; it < KNN; ++it) {
                unsigned long long g = umin64(umin64(cc[0], cc[1]), umin64(cc[2], cc[3]));
#pragma unroll
                for (int o = 1; o < 64; o <<= 1) g = umin64(g, __shfl_xor(g, o));
                if (tid == 0) idx_out[row * KNN + it] = (int)(unsigned)(g & 0xFFFFFFFFull);
#pragma unroll
                for (int q = 0; q < 4; ++q) if (cc[q] == g) cc[q] = ~0ull;
            }
        }
    } else {
        // exact fallback (massive ties) — not expected on this data; cand[0..3] as partials
        for (int it = 0; it < KNN; ++it) {
            unsigned long long best = ~0ull;
            for (int m = 0; m < NPTS / 256; ++m) {
                int j = tid + 256 * m;
                best = umin64(best, (((unsigned long long)keys[j]) << 32) | (unsigned)j);
            }
#pragma unroll
            for (int o = 1; o < 64; o <<= 1) best = umin64(best, __shfl_xor(best, o));
            if ((tid & 63) == 0) cand[tid >> 6] = best;
            __syncthreads();
            unsigned long long g = umin64(umin64(cand[0], cand[1]), umin64(cand[2], cand[3]));
            int j = (int)(unsigned)(g & 0xFFFFFFFFull);
            if (tid == 0) idx_out[row * KNN + it] = j;
            __syncthreads();
            if (tid == (j & 255)) keys[j] = 0xFFFFFFFFu;
            __syncthreads();
        }
    }
}

// ---------------- stage-1 fused: C=3 distances + top-K, no dist materialization ----------------
__global__ __launch_bounds__(256) void knn3_fused_kernel(const float* __restrict__ X,
                                                         const float* __restrict__ x2,
                                                         int* __restrict__ idx_out) {
    __shared__ unsigned int keys[NPTS];
    __shared__ unsigned int ured[4];
    __shared__ unsigned long long cand[CAP];
    __shared__ int scal[8];
    const int tid = threadIdx.x;
    const int row = blockIdx.x;
    const float xi0 = X[(long)row * 3], xi1 = X[(long)row * 3 + 1], xi2 = X[(long)row * 3 + 2];
    const float x2i = x2[row];

    for (int m = 0; m < NPTS / 256; ++m) {
        int j = tid + 256 * m;
        float accv = 0.f;
        accv = fmaf(xi0, X[(long)j * 3], accv);
        accv = fmaf(xi1, X[(long)j * 3 + 1], accv);
        accv = fmaf(xi2, X[(long)j * 3 + 2], accv);
        float d = (x2i + x2[j]) - 2.f * accv;
        unsigned u = __float_as_uint(d);
        keys[j] = (u & 0x80000000u) ? ~u : (u | 0x80000000u);
    }
    __syncthreads();
    sample_select20(keys, ured, cand, scal, row, idx_out);
}

// ---------------- pairwise distance (fp32), 128x128 tile, 8x8 microtile, BK=16 prefetch ----------------
__global__ __launch_bounds__(256) void dist128_kernel(const float* __restrict__ X, int ld, int C,
                                                      const float* __restrict__ x2,
                                                      float* __restrict__ dist, int i0base) {
    __shared__ float As[16][132];
    __shared__ float Bs[16][132];
    const int tid = threadIdx.x;
    const int i0 = i0base + blockIdx.y * 128;
    const int j0 = blockIdx.x * 128;
    const int ty = tid >> 4, tx = tid & 15;
    const int lc = tid & 15, lr = tid >> 4;

    float ra[8], rb[8];
    float acc[8][8];
#pragma unroll
    for (int a = 0; a < 8; ++a)
#pragma unroll
        for (int b = 0; b < 8; ++b) acc[a][b] = 0.f;

    {
        const bool v = (lc < C);
#pragma unroll
        for (int q = 0; q < 8; ++q) {
            int r = lr + 16 * q;
            ra[q] = v ? X[(long)(i0 + r) * ld + lc] : 0.f;
            rb[q] = v ? X[(long)(j0 + r) * ld + lc] : 0.f;
        }
    }

    for (int k0 = 0; k0 < C; k0 += 16) {
#pragma unroll
        for (int q = 0; q < 8; ++q) {
            As[lc][lr + 16 * q] = ra[q];
            Bs[lc][lr + 16 * q] = rb[q];
        }
        __syncthreads();
        if (k0 + 16 < C) {
            const bool v = (k0 + 16 + lc < C);
#pragma unroll
            for (int q = 0; q < 8; ++q) {
                int r = lr + 16 * q;
                ra[q] = v ? X[(long)(i0 + r) * ld + k0 + 16 + lc] : 0.f;
                rb[q] = v ? X[(long)(j0 + r) * ld + k0 + 16 + lc] : 0.f;
            }
        }
#pragma unroll
        for (int kk = 0; kk < 16; ++kk) {
            float4 a0 = *(const float4*)&As[kk][ty * 8];
            float4 a1 = *(const float4*)&As[kk][ty * 8 + 4];
            float4 b0 = *(const float4*)&Bs[kk][tx * 8];
            float4 b1 = *(const float4*)&Bs[kk][tx * 8 + 4];
            float av[8] = {a0.x, a0.y, a0.z, a0.w, a1.x, a1.y, a1.z, a1.w};
            float bv[8] = {b0.x, b0.y, b0.z, b0.w, b1.x, b1.y, b1.z, b1.w};
#pragma unroll
            for (int ii = 0; ii < 8; ++ii)
#pragma unroll
                for (int jj = 0; jj < 8; ++jj)
                    acc[ii][jj] = fmaf(av[ii], bv[jj], acc[ii][jj]);
        }
        __syncthreads();
    }

    float xj[8];
#pragma unroll
    for (int jj = 0; jj < 8; ++jj) xj[jj] = x2[j0 + tx * 8 + jj];
#pragma unroll
    for (int ii = 0; ii < 8; ++ii) {
        int rloc = blockIdx.y * 128 + ty * 8 + ii;
        float xi = x2[i0base + rloc];
        float4 o0, o1;
        o0.x = (xi + xj[0]) - 2.f * acc[ii][0];
        o0.y = (xi + xj[1]) - 2.f * acc[ii][1];
        o0.z = (xi + xj[2]) - 2.f * acc[ii][2];
        o0.w = (xi + xj[3]) - 2.f * acc[ii][3];
        o1.x = (xi + xj[4]) - 2.f * acc[ii][4];
        o1.y = (xi + xj[5]) - 2.f * acc[ii][5];
        o1.z = (xi + xj[6]) - 2.f * acc[ii][6];
        o1.w = (xi + xj[7]) - 2.f * acc[ii][7];
        *(float4*)&dist[(long)rloc * NPTS + j0 + tx * 8] = o0;
        *(float4*)&dist[(long)rloc * NPTS + j0 + tx * 8 + 4] = o1;
    }
}

// ---------------- top-K from materialized dist rows ----------------
__global__ __launch_bounds__(256) void topk_kernel(const float* __restrict__ dist, int* __restrict__ idx_out,
                                                   int rowbase) {
    __shared__ unsigned int keys[NPTS];
    __shared__ unsigned int ured[4];
    __shared__ unsigned long long cand[CAP];
    __shared__ int scal[8];
    const int tid = threadIdx.x;
    const long row = rowbase + blockIdx.x;
    const float* drow = dist + (long)blockIdx.x * NPTS;

    for (int m = 0; m < NPTS / 256; ++m) {
        int j = tid + 256 * m;
        unsigned u = __float_as_uint(drow[j]);
        keys[j] = (u & 0x80000000u) ? ~u : (u | 0x80000000u);
    }
    __syncthreads();
    sample_select20(keys, ured, cand, scal, row, idx_out);
}

// ---------------- erosion edge-conv (fp32, order-free exact) ----------------
template<int F, int C>
__global__ void erode_kernel(const float* __restrict__ X, int ld, const int* __restrict__ idx,
                             const float* __restrict__ w, float* __restrict__ out, int ldo) {
    __shared__ int nidx[KNN];
    __shared__ float neigh[KNN * C];
    const int tid = threadIdx.x;
    const int row = blockIdx.x;
    if (tid < KNN) nidx[tid] = idx[row * KNN + tid];
    __syncthreads();
    for (int t = tid; t < KNN * C; t += blockDim.x) {
        int k = t / C, c = t % C;
        neigh[t] = X[(long)nidx[k] * ld + c];
    }
    __syncthreads();
    if (tid < F * C) {
        int f = tid / C, c = tid % C;
        float m = neigh[c] - w[f * KNN * C + c];
        for (int k = 1; k < KNN; ++k)
            m = fminf(m, neigh[k * C + c] - w[(f * KNN + k) * C + c]);
        out[(long)row * ldo + tid] = m;
    }
}

// ---------------- fp32 GEMM 128x128 (lin1), BK=16 prefetch, bias+ReLU ----------------
template<int RELU>
__global__ __launch_bounds__(256) void gemm128_kernel(const float* __restrict__ A, const float* __restrict__ B,
                                                      const float* __restrict__ bias, float* __restrict__ Cm,
                                                      int K, int N) {
    __shared__ float As[16][132];
    __shared__ float Bs[16][132];
    const int tid = threadIdx.x;
    const int i0 = blockIdx.y * 128, j0 = blockIdx.x * 128;
    const int ty = tid >> 4, tx = tid & 15;
    const int lc = tid & 15, lr = tid >> 4;
    const int lb_n = tid & 127, lb_k = tid >> 7;

    float ra[8], rb[8];
    float acc[8][8];
#pragma unroll
    for (int a = 0; a < 8; ++a)
#pragma unroll
        for (int b = 0; b < 8; ++b) acc[a][b] = 0.f;

    {
        const bool bn = (j0 + lb_n < N);
#pragma unroll
        for (int q = 0; q < 8; ++q) {
            int r = lr + 16 * q;
            ra[q] = (lc < K) ? A[(long)(i0 + r) * K + lc] : 0.f;
            int kk = lb_k + 2 * q;
            rb[q] = (kk < K && bn) ? B[(long)kk * N + j0 + lb_n] : 0.f;
        }
    }

    for (int k0 = 0; k0 < K; k0 += 16) {
#pragma unroll
        for (int q = 0; q < 8; ++q) {
            As[lc][lr + 16 * q] = ra[q];
            Bs[lb_k + 2 * q][lb_n] = rb[q];
        }
        __syncthreads();
        if (k0 + 16 < K) {
            const bool bn = (j0 + lb_n < N);
#pragma unroll
            for (int q = 0; q < 8; ++q) {
                int r = lr + 16 * q;
                ra[q] = (k0 + 16 + lc < K) ? A[(long)(i0 + r) * K + k0 + 16 + lc] : 0.f;
                int kk = k0 + 16 + lb_k + 2 * q;
                rb[q] = (kk < K && bn) ? B[(long)kk * N + j0 + lb_n] : 0.f;
            }
        }
#pragma unroll
        for (int kk = 0; kk < 16; ++kk) {
            float4 a0 = *(const float4*)&As[kk][ty * 8];
            float4 a1 = *(const float4*)&As[kk][ty * 8 + 4];
            float4 b0 = *(const float4*)&Bs[kk][tx * 8];
            float4 b1 = *(const float4*)&Bs[kk][tx * 8 + 4];
            float av[8] = {a0.x, a0.y, a0.z, a0.w, a1.x, a1.y, a1.z, a1.w};
            float bv[8] = {b0.x, b0.y, b0.z, b0.w, b1.x, b1.y, b1.z, b1.w};
#pragma unroll
            for (int ii = 0; ii < 8; ++ii)
#pragma unroll
                for (int jj = 0; jj < 8; ++jj)
                    acc[ii][jj] = fmaf(av[ii], bv[jj], acc[ii][jj]);
        }
        __syncthreads();
    }

#pragma unroll
    for (int ii = 0; ii < 8; ++ii) {
        int i = i0 + ty * 8 + ii;
#pragma unroll
        for (int jj = 0; jj < 8; ++jj) {
            int j = j0 + tx * 8 + jj;
            if (j < N) {
                float v = acc[ii][jj] + bias[j];
                if (RELU) v = fmaxf(v, 0.f);
                Cm[(long)i * N + j] = v;
            }
        }
    }
}

// ---------------- fp32 GEMM 64x64 (layers 2-4), BK=32 prefetch ----------------
template<int RELU>
__global__ __launch_bounds__(256) void gemm_kernel(const float* __restrict__ A, const float* __restrict__ B,
                                                   const float* __restrict__ bias, float* __restrict__ Cm,
                                                   int K, int N) {
    __shared__ float As[32][68];
    __shared__ float Bs[32][68];
    const int tid = threadIdx.x;
    const int i0 = blockIdx.y * 64, j0 = blockIdx.x * 64;
    const int ty = tid >> 4, tx = tid & 15;
    const int la_c = tid & 31, la_r = tid >> 5;
    const int lb_n = tid & 63, lb_k = tid >> 6;

    float ra[8], rb[8];
    float acc[4][4];
#pragma unroll
    for (int a = 0; a < 4; ++a)
#pragma unroll
        for (int b = 0; b < 4; ++b) acc[a][b] = 0.f;

    {
        const bool bn = (j0 + lb_n < N);
#pragma unroll
        for (int q = 0; q < 8; ++q) {
            int r = la_r + 8 * q;
            ra[q] = (la_c < K) ? A[(long)(i0 + r) * K + la_c] : 0.f;
            int kk = lb_k + 4 * q;
            rb[q] = (kk < K && bn) ? B[(long)kk * N + j0 + lb_n] : 0.f;
        }
    }

    for (int k0 = 0; k0 < K; k0 += 32) {
#pragma unroll
        for (int q = 0; q < 8; ++q) {
            As[la_c][la_r + 8 * q] = ra[q];
            Bs[lb_k + 4 * q][lb_n] = rb[q];
        }
        __syncthreads();
        if (k0 + 32 < K) {
            const bool bn = (j0 + lb_n < N);
#pragma unroll
            for (int q = 0; q < 8; ++q) {
                int r = la_r + 8 * q;
                ra[q] = (k0 + 32 + la_c < K) ? A[(long)(i0 + r) * K + k0 + 32 + la_c] : 0.f;
                int kk = k0 + 32 + lb_k + 4 * q;
                rb[q] = (kk < K && bn) ? B[(long)kk * N + j0 + lb_n] : 0.f;
            }
        }
#pragma unroll
        for (int kk = 0; kk < 32; ++kk) {
            float4 a4 = *(const float4*)&As[kk][ty * 4];
            float4 b4 = *(const float4*)&Bs[kk][tx * 4];
            float av[4] = {a4.x, a4.y, a4.z, a4.w};
            float bv[4] = {b4.x, b4.y, b4.z, b4.w};
#pragma unroll
            for (int ii = 0; ii < 4; ++ii)
#pragma unroll
                for (int jj = 0; jj < 4; ++jj)
                    acc[ii][jj] = fmaf(av[ii], bv[jj], acc[ii][jj]);
        }
        __syncthreads();
    }

#pragma unroll
    for (int ii = 0; ii < 4; ++ii) {
        int i = i0 + ty * 4 + ii;
#pragma unroll
        for (int jj = 0; jj < 4; ++jj) {
            int j = j0 + tx * 4 + jj;
            if (j < N) {
                float v = acc[ii][jj] + bias[j];
                if (RELU) v = fmaxf(v, 0.f);
                Cm[(long)i * N + j] = v;
            }
        }
    }
}

// ---------------- log_softmax over 40 cols, wave per row, in place ----------------
__global__ void logsoftmax_kernel(float* __restrict__ out) {
    const int lane = threadIdx.x & 63;
    const int wid = threadIdx.x >> 6;
    const int row = blockIdx.x * 4 + wid;
    float* o = out + (long)row * 40;
    float v = (lane < 40) ? o[lane] : -INFINITY;
    float m = v;
#pragma unroll
    for (int off = 1; off < 64; off <<= 1) m = fmaxf(m, __shfl_xor(m, off));
    float e = (lane < 40) ? expf(v - m) : 0.f;
    float s = e;
#pragma unroll
    for (int off = 1; off < 64; off <<= 1) s += __shfl_xor(s, off);
    float r = (v - m) - logf(s);
    if (lane < 40) o[lane] = r;
}

extern "C" void kernel_launch(void* const* d_in, const int* in_sizes, int n_in,
                              void* d_out, int out_size, void* d_ws, size_t ws_size,
                              hipStream_t stream) {
    (void)in_sizes; (void)n_in; (void)out_size;
    const float* x     = (const float*)d_in[0];
    const float* w1    = (const float*)d_in[1];
    const float* w2    = (const float*)d_in[2];
    const float* w3    = (const float*)d_in[3];
    const float* lin1w = (const float*)d_in[4];
    const float* lin1b = (const float*)d_in[5];
    const float* wa    = (const float*)d_in[6];
    const float* ba    = (const float*)d_in[7];
    const float* wb    = (const float*)d_in[8];
    const float* bb    = (const float*)d_in[9];
    const float* wo    = (const float*)d_in[10];
    const float* bo    = (const float*)d_in[11];
    float* outp = (float*)d_out;

    // ---- ws_size-adaptive layout ----
    char* ws = (char*)d_ws;
    size_t off = 0;
    auto take = [&](size_t bytes) { char* p = ws + off; off += (bytes + 255) & ~(size_t)255; return p; };
    float* x2  = (float*)take((size_t)NPTS * 4);
    int*   idx = (int*)  take((size_t)NPTS * KNN * 4);
    float* h0  = (float*)take((size_t)NPTS * 420 * 4);
    size_t rest = (ws_size > off) ? (ws_size - off) : 0;
    char*  scratch = ws + off;

    int cr = (int)(rest / ((size_t)NPTS * 4));   // fp32 dist chunk rows
    if (cr > 4096) cr = 4096;                    // 128 MB chunk: topk re-read stays L3-resident
    cr &= ~127;
    if (cr < 128) cr = 128;
    float* dist = (float*)scratch;

    int mr = (int)(rest / 5632);                 // fp32 MLP chunk rows
    if (mr > NPTS) mr = NPTS;
    mr &= ~127;
    if (mr < 128) mr = 128;

    dim3 b256(256);
    dim3 grow(NPTS);

    // ---- stage 1: fused knn(x, C=3) -> erode -> x1 = h0[:, 0:60]
    rowsq_np_kernel<3><<<dim3(32), b256, 0, stream>>>(x, 3, x2);
    knn3_fused_kernel<<<grow, b256, 0, stream>>>(x, x2, idx);
    erode_kernel<20, 3><<<grow, dim3(64), 0, stream>>>(x, 3, idx, w1, h0 + 0, 420);

    // ---- stage 2: knn(x1, C=60) -> erode -> x2f = h0[:, 60:180]
    rowsq_np_kernel<60><<<dim3(32), b256, 0, stream>>>(h0, 420, x2);
    for (int r0 = 0; r0 < NPTS; r0 += cr) {
        int rows = (NPTS - r0 < cr) ? (NPTS - r0) : cr;
        dist128_kernel<<<dim3(64, rows / 128), b256, 0, stream>>>(h0, 420, 60, x2, dist, r0);
        topk_kernel<<<dim3(rows), b256, 0, stream>>>(dist, idx, r0);
    }
    erode_kernel<2, 60><<<grow, dim3(128), 0, stream>>>(h0, 420, idx, w2, h0 + 60, 420);

    // ---- stage 3: knn(x2f, C=120) -> erode -> x3 = h0[:, 180:420]
    rowsq_np_kernel<120><<<dim3(32), b256, 0, stream>>>(h0 + 60, 420, x2);
    for (int r0 = 0; r0 < NPTS; r0 += cr) {
        int rows = (NPTS - r0 < cr) ? (NPTS - r0) : cr;
        dist128_kernel<<<dim3(64, rows / 128), b256, 0, stream>>>(h0 + 60, 420, 120, x2, dist, r0);
        topk_kernel<<<dim3(rows), b256, 0, stream>>>(dist, idx, r0);
    }
    erode_kernel<2, 120><<<grow, dim3(256), 0, stream>>>(h0 + 60, 420, idx, w3, h0 + 180, 420);

    // ---- MLP (row-chunked; h1|h2|h3 live in scratch)
    for (int r0 = 0; r0 < NPTS; r0 += mr) {
        int rows = (NPTS - r0 < mr) ? (NPTS - r0) : mr;
        float* h1c = (float*)scratch;
        float* h2c = h1c + (size_t)mr * 1024;
        float* h3c = h2c + (size_t)mr * 256;
        gemm128_kernel<1><<<dim3(8, rows / 128), b256, 0, stream>>>(h0 + (long)r0 * 420, lin1w, lin1b, h1c, 420, 1024);
        gemm_kernel<1><<<dim3(4, rows / 64), b256, 0, stream>>>(h1c, wa, ba, h2c, 1024, 256);
        gemm_kernel<1><<<dim3(2, rows / 64), b256, 0, stream>>>(h2c, wb, bb, h3c, 256, 128);
        gemm_kernel<0><<<dim3(1, rows / 64), b256, 0, stream>>>(h3c, wo, bo, outp + (long)r0 * 40, 128, 40);
        logsoftmax_kernel<<<dim3(rows / 4), b256, 0, stream>>>(outp + (long)r0 * 40);
    }
}

// Round 10
// 1041.360 us; speedup vs baseline: 1.4255x; 1.0824x over previous
//
#include <hip/hip_runtime.h>
#include <math.h>

#define NPTS 8192
#define KNN 20
#define CAP 256
#define NT 512               // threads for select kernels
#define MK (NPTS / NT)       // 16 keys per thread (registers)
#define NW (NT / 64)         // 8 waves

static __device__ __forceinline__ unsigned long long umin64(unsigned long long a, unsigned long long b) {
    return a < b ? a : b;
}
static __device__ __forceinline__ unsigned umin32(unsigned a, unsigned b) { return a < b ? a : b; }

// ---------------- row squared norms: bit-faithful replica of np.sum(x*x, -1) ----------------
template<int C>
__global__ void rowsq_np_kernel(const float* __restrict__ X, int ld, float* __restrict__ x2) {
#pragma clang fp contract(off)
    int i = blockIdx.x * blockDim.x + threadIdx.x;
    if (i >= NPTS) return;
    const float* row = X + (long)i * ld;
    float res;
    if (C < 8) {
        res = 0.f;
        for (int c = 0; c < C; ++c) res += row[c] * row[c];
    } else {
        float r[8];
#pragma unroll
        for (int j = 0; j < 8; ++j) r[j] = row[j] * row[j];
        int p = 8;
        for (; p < C - (C % 8); p += 8)
#pragma unroll
            for (int j = 0; j < 8; ++j) r[j] += row[p + j] * row[p + j];
        res = ((r[0] + r[1]) + (r[2] + r[3])) + ((r[4] + r[5]) + (r[6] + r[7]));
        for (; p < C; ++p) res += row[p] * row[p];
    }
    x2[i] = res;
}

// ---------------- X -> SoA (C=3) ----------------
__global__ void soa3_kernel(const float* __restrict__ X, float* __restrict__ X0,
                            float* __restrict__ X1, float* __restrict__ X2) {
    int i = blockIdx.x * blockDim.x + threadIdx.x;
    if (i < NPTS) { X0[i] = X[3 * i]; X1[i] = X[3 * i + 1]; X2[i] = X[3 * i + 2]; }
}

// ---------------- register-resident count of keys <= B ----------------
__device__ __forceinline__ int count_le_reg(const unsigned* k, unsigned B, int* scal) {
    const int tid = threadIdx.x;
    int cnt = 0;
#pragma unroll
    for (int m = 0; m < MK; ++m) cnt += (k[m] <= B) ? 1 : 0;
#pragma unroll
    for (int o = 32; o >= 1; o >>= 1) cnt += __shfl_down(cnt, (unsigned)o);
    if ((tid & 63) == 0) scal[tid >> 6] = cnt;
    __syncthreads();
    int tot = 0;
#pragma unroll
    for (int w = 0; w < NW; ++w) tot += scal[w];
    __syncthreads();
    return tot;
}

// ---------------- exact top-K via min-scan sample threshold, keys in REGISTERS ----------------
// Same algorithm as round 9 (identical selected indices): B = smallest active sample
// with count(keys<=B) >= KNN; candidates <= B collected; exact (key,idx)-ascending
// extraction over <=CAP candidates; exact 20-round fallback if count > CAP.
__device__ __forceinline__ void select20_reg(unsigned* k, unsigned* ured,
                                             unsigned long long* cand, int* scal,
                                             long row, int* __restrict__ idx_out) {
    const int tid = threadIdx.x;
    unsigned s = k[0];              // one sample per thread (j = tid)
    unsigned B; int c;
    for (;;) {
        unsigned m = s;
#pragma unroll
        for (int o = 32; o >= 1; o >>= 1) m = umin32(m, __shfl_down(m, (unsigned)o));
        if ((tid & 63) == 0) ured[tid >> 6] = m;
        __syncthreads();
        B = ured[0];
#pragma unroll
        for (int w = 1; w < NW; ++w) B = umin32(B, ured[w]);
        __syncthreads();
        c = count_le_reg(k, B, scal);
        if (c >= KNN) break;
        if (s <= B) s = 0xFFFFFFFFu;   // deactivate exhausted samples
    }
    if (tid == 0) scal[8] = 0;
    __syncthreads();

    if (c <= CAP) {
#pragma unroll
        for (int m = 0; m < MK; ++m) {
            if (k[m] <= B) {
                int j = tid + NT * m;
                int p = atomicAdd(&scal[8], 1);    // p < c <= CAP guaranteed
                cand[p] = (((unsigned long long)k[m]) << 32) | (unsigned)j;
            }
        }
        __syncthreads();
        const int nc = scal[8];
        if (tid < 64) {
            unsigned long long cc[4];
#pragma unroll
            for (int q = 0; q < 4; ++q) { int i = tid + 64 * q; cc[q] = (i < nc) ? cand[i] : ~0ull; }
            for (int it = 0; it < KNN; ++it) {
                unsigned long long g = umin64(umin64(cc[0], cc[1]), umin64(cc[2], cc[3]));
#pragma unroll
                for (int o = 1; o < 64; o <<= 1) g = umin64(g, __shfl_xor(g, o));
                if (tid == 0) idx_out[row * KNN + it] = (int)(unsigned)(g & 0xFFFFFFFFull);
#pragma unroll
                for (int q = 0; q < 4; ++q) if (cc[q] == g) cc[q] = ~0ull;
            }
        }
    } else {
        // exact fallback (massive ties) — not expected; cand[0..NW) reused as partials
        for (int it = 0; it < KNN; ++it) {
            unsigned long long best = ~0ull;
#pragma unroll
            for (int m = 0; m < MK; ++m)
                best = umin64(best, (((unsigned long long)k[m]) << 32) | (unsigned)(tid + NT * m));
#pragma unroll
            for (int o = 1; o < 64; o <<= 1) best = umin64(best, __shfl_xor(best, o));
            if ((tid & 63) == 0) cand[tid >> 6] = best;
            __syncthreads();
            unsigned long long g = cand[0];
#pragma unroll
            for (int w = 1; w < NW; ++w) g = umin64(g, cand[w]);
            int j = (int)(unsigned)(g & 0xFFFFFFFFull);
            if (tid == 0) idx_out[row * KNN + it] = j;
            __syncthreads();
            // unrolled compare-select keeps k[] in registers (no dynamic indexing)
            int mi = j / NT;
#pragma unroll
            for (int m = 0; m < MK; ++m)
                if (m == mi && tid == (j & (NT - 1))) k[m] = 0xFFFFFFFFu;
            __syncthreads();
        }
    }
}

// ---------------- stage-1 fused: C=3 distances (SoA) + top-K, keys in registers ----------------
__global__ __launch_bounds__(NT) void knn3_fused_kernel(const float* __restrict__ X0,
                                                        const float* __restrict__ X1,
                                                        const float* __restrict__ X2,
                                                        const float* __restrict__ x2,
                                                        int* __restrict__ idx_out) {
    __shared__ unsigned ured[NW];
    __shared__ unsigned long long cand[CAP];
    __shared__ int scal[16];
    unsigned k[MK];
    const int tid = threadIdx.x;
    const int row = blockIdx.x;
    const float xi0 = X0[row], xi1 = X1[row], xi2 = X2[row];
    const float x2i = x2[row];

#pragma unroll
    for (int m = 0; m < MK; ++m) {
        int j = tid + NT * m;
        float accv = 0.f;                       // identical ascending-c fmaf chain
        accv = fmaf(xi0, X0[j], accv);
        accv = fmaf(xi1, X1[j], accv);
        accv = fmaf(xi2, X2[j], accv);
        float d = (x2i + x2[j]) - 2.f * accv;
        unsigned u = __float_as_uint(d);
        k[m] = (u & 0x80000000u) ? ~u : (u | 0x80000000u);
    }
    select20_reg(k, ured, cand, scal, row, idx_out);
}

// ---------------- top-K from materialized dist rows, keys in registers ----------------
__global__ __launch_bounds__(NT) void topk_kernel(const float* __restrict__ dist, int* __restrict__ idx_out,
                                                  int rowbase) {
    __shared__ unsigned ured[NW];
    __shared__ unsigned long long cand[CAP];
    __shared__ int scal[16];
    unsigned k[MK];
    const int tid = threadIdx.x;
    const long row = rowbase + blockIdx.x;
    const float* drow = dist + (long)blockIdx.x * NPTS;

#pragma unroll
    for (int m = 0; m < MK; ++m) {
        unsigned u = __float_as_uint(drow[tid + NT * m]);
        k[m] = (u & 0x80000000u) ? ~u : (u | 0x80000000u);
    }
    select20_reg(k, ured, cand, scal, row, idx_out);
}

// ---------------- pairwise distance (fp32), 128x128 tile, 8x8 microtile, BK=16 prefetch ----------------
__global__ __launch_bounds__(256) void dist128_kernel(const float* __restrict__ X, int ld, int C,
                                                      const float* __restrict__ x2,
                                                      float* __restrict__ dist, int i0base) {
    __shared__ float As[16][132];
    __shared__ float Bs[16][132];
    const int tid = threadIdx.x;
    const int i0 = i0base + blockIdx.y * 128;
    const int j0 = blockIdx.x * 128;
    const int ty = tid >> 4, tx = tid & 15;
    const int lc = tid & 15, lr = tid >> 4;

    float ra[8], rb[8];
    float acc[8][8];
#pragma unroll
    for (int a = 0; a < 8; ++a)
#pragma unroll
        for (int b = 0; b < 8; ++b) acc[a][b] = 0.f;

    {
        const bool v = (lc < C);
#pragma unroll
        for (int q = 0; q < 8; ++q) {
            int r = lr + 16 * q;
            ra[q] = v ? X[(long)(i0 + r) * ld + lc] : 0.f;
            rb[q] = v ? X[(long)(j0 + r) * ld + lc] : 0.f;
        }
    }

    for (int k0 = 0; k0 < C; k0 += 16) {
#pragma unroll
        for (int q = 0; q < 8; ++q) {
            As[lc][lr + 16 * q] = ra[q];
            Bs[lc][lr + 16 * q] = rb[q];
        }
        __syncthreads();
        if (k0 + 16 < C) {
            const bool v = (k0 + 16 + lc < C);
#pragma unroll
            for (int q = 0; q < 8; ++q) {
                int r = lr + 16 * q;
                ra[q] = v ? X[(long)(i0 + r) * ld + k0 + 16 + lc] : 0.f;
                rb[q] = v ? X[(long)(j0 + r) * ld + k0 + 16 + lc] : 0.f;
            }
        }
#pragma unroll
        for (int kk = 0; kk < 16; ++kk) {
            float4 a0 = *(const float4*)&As[kk][ty * 8];
            float4 a1 = *(const float4*)&As[kk][ty * 8 + 4];
            float4 b0 = *(const float4*)&Bs[kk][tx * 8];
            float4 b1 = *(const float4*)&Bs[kk][tx * 8 + 4];
            float av[8] = {a0.x, a0.y, a0.z, a0.w, a1.x, a1.y, a1.z, a1.w};
            float bv[8] = {b0.x, b0.y, b0.z, b0.w, b1.x, b1.y, b1.z, b1.w};
#pragma unroll
            for (int ii = 0; ii < 8; ++ii)
#pragma unroll
                for (int jj = 0; jj < 8; ++jj)
                    acc[ii][jj] = fmaf(av[ii], bv[jj], acc[ii][jj]);
        }
        __syncthreads();
    }

    float xj[8];
#pragma unroll
    for (int jj = 0; jj < 8; ++jj) xj[jj] = x2[j0 + tx * 8 + jj];
#pragma unroll
    for (int ii = 0; ii < 8; ++ii) {
        int rloc = blockIdx.y * 128 + ty * 8 + ii;
        float xi = x2[i0base + rloc];
        float4 o0, o1;
        o0.x = (xi + xj[0]) - 2.f * acc[ii][0];
        o0.y = (xi + xj[1]) - 2.f * acc[ii][1];
        o0.z = (xi + xj[2]) - 2.f * acc[ii][2];
        o0.w = (xi + xj[3]) - 2.f * acc[ii][3];
        o1.x = (xi + xj[4]) - 2.f * acc[ii][4];
        o1.y = (xi + xj[5]) - 2.f * acc[ii][5];
        o1.z = (xi + xj[6]) - 2.f * acc[ii][6];
        o1.w = (xi + xj[7]) - 2.f * acc[ii][7];
        *(float4*)&dist[(long)rloc * NPTS + j0 + tx * 8] = o0;
        *(float4*)&dist[(long)rloc * NPTS + j0 + tx * 8 + 4] = o1;
    }
}

// ---------------- erosion edge-conv (fp32, order-free exact) ----------------
template<int F, int C>
__global__ void erode_kernel(const float* __restrict__ X, int ld, const int* __restrict__ idx,
                             const float* __restrict__ w, float* __restrict__ out, int ldo) {
    __shared__ int nidx[KNN];
    __shared__ float neigh[KNN * C];
    const int tid = threadIdx.x;
    const int row = blockIdx.x;
    if (tid < KNN) nidx[tid] = idx[row * KNN + tid];
    __syncthreads();
    for (int t = tid; t < KNN * C; t += blockDim.x) {
        int k = t / C, c = t % C;
        neigh[t] = X[(long)nidx[k] * ld + c];
    }
    __syncthreads();
    if (tid < F * C) {
        int f = tid / C, c = tid % C;
        float m = neigh[c] - w[f * KNN * C + c];
        for (int k = 1; k < KNN; ++k)
            m = fminf(m, neigh[k * C + c] - w[(f * KNN + k) * C + c]);
        out[(long)row * ldo + tid] = m;
    }
}

// ---------------- fp32 GEMM 128x128 (lin1), BK=16 prefetch, bias+ReLU ----------------
template<int RELU>
__global__ __launch_bounds__(256) void gemm128_kernel(const float* __restrict__ A, const float* __restrict__ B,
                                                      const float* __restrict__ bias, float* __restrict__ Cm,
                                                      int K, int N) {
    __shared__ float As[16][132];
    __shared__ float Bs[16][132];
    const int tid = threadIdx.x;
    const int i0 = blockIdx.y * 128, j0 = blockIdx.x * 128;
    const int ty = tid >> 4, tx = tid & 15;
    const int lc = tid & 15, lr = tid >> 4;
    const int lb_n = tid & 127, lb_k = tid >> 7;

    float ra[8], rb[8];
    float acc[8][8];
#pragma unroll
    for (int a = 0; a < 8; ++a)
#pragma unroll
        for (int b = 0; b < 8; ++b) acc[a][b] = 0.f;

    {
        const bool bn = (j0 + lb_n < N);
#pragma unroll
        for (int q = 0; q < 8; ++q) {
            int r = lr + 16 * q;
            ra[q] = (lc < K) ? A[(long)(i0 + r) * K + lc] : 0.f;
            int kk = lb_k + 2 * q;
            rb[q] = (kk < K && bn) ? B[(long)kk * N + j0 + lb_n] : 0.f;
        }
    }

    for (int k0 = 0; k0 < K; k0 += 16) {
#pragma unroll
        for (int q = 0; q < 8; ++q) {
            As[lc][lr + 16 * q] = ra[q];
            Bs[lb_k + 2 * q][lb_n] = rb[q];
        }
        __syncthreads();
        if (k0 + 16 < K) {
            const bool bn = (j0 + lb_n < N);
#pragma unroll
            for (int q = 0; q < 8; ++q) {
                int r = lr + 16 * q;
                ra[q] = (k0 + 16 + lc < K) ? A[(long)(i0 + r) * K + k0 + 16 + lc] : 0.f;
                int kk = k0 + 16 + lb_k + 2 * q;
                rb[q] = (kk < K && bn) ? B[(long)kk * N + j0 + lb_n] : 0.f;
            }
        }
#pragma unroll
        for (int kk = 0; kk < 16; ++kk) {
            float4 a0 = *(const float4*)&As[kk][ty * 8];
            float4 a1 = *(const float4*)&As[kk][ty * 8 + 4];
            float4 b0 = *(const float4*)&Bs[kk][tx * 8];
            float4 b1 = *(const float4*)&Bs[kk][tx * 8 + 4];
            float av[8] = {a0.x, a0.y, a0.z, a0.w, a1.x, a1.y, a1.z, a1.w};
            float bv[8] = {b0.x, b0.y, b0.z, b0.w, b1.x, b1.y, b1.z, b1.w};
#pragma unroll
            for (int ii = 0; ii < 8; ++ii)
#pragma unroll
                for (int jj = 0; jj < 8; ++jj)
                    acc[ii][jj] = fmaf(av[ii], bv[jj], acc[ii][jj]);
        }
        __syncthreads();
    }

#pragma unroll
    for (int ii = 0; ii < 8; ++ii) {
        int i = i0 + ty * 8 + ii;
#pragma unroll
        for (int jj = 0; jj < 8; ++jj) {
            int j = j0 + tx * 8 + jj;
            if (j < N) {
                float v = acc[ii][jj] + bias[j];
                if (RELU) v = fmaxf(v, 0.f);
                Cm[(long)i * N + j] = v;
            }
        }
    }
}

// ---------------- fp32 GEMM 64x64 (layers 2-4), BK=32 prefetch ----------------
template<int RELU>
__global__ __launch_bounds__(256) void gemm_kernel(const float* __restrict__ A, const float* __restrict__ B,
                                                   const float* __restrict__ bias, float* __restrict__ Cm,
                                                   int K, int N) {
    __shared__ float As[32][68];
    __shared__ float Bs[32][68];
    const int tid = threadIdx.x;
    const int i0 = blockIdx.y * 64, j0 = blockIdx.x * 64;
    const int ty = tid >> 4, tx = tid & 15;
    const int la_c = tid & 31, la_r = tid >> 5;
    const int lb_n = tid & 63, lb_k = tid >> 6;

    float ra[8], rb[8];
    float acc[4][4];
#pragma unroll
    for (int a = 0; a < 4; ++a)
#pragma unroll
        for (int b = 0; b < 4; ++b) acc[a][b] = 0.f;

    {
        const bool bn = (j0 + lb_n < N);
#pragma unroll
        for (int q = 0; q < 8; ++q) {
            int r = la_r + 8 * q;
            ra[q] = (la_c < K) ? A[(long)(i0 + r) * K + la_c] : 0.f;
            int kk = lb_k + 4 * q;
            rb[q] = (kk < K && bn) ? B[(long)kk * N + j0 + lb_n] : 0.f;
        }
    }

    for (int k0 = 0; k0 < K; k0 += 32) {
#pragma unroll
        for (int q = 0; q < 8; ++q) {
            As[la_c][la_r + 8 * q] = ra[q];
            Bs[lb_k + 4 * q][lb_n] = rb[q];
        }
        __syncthreads();
        if (k0 + 32 < K) {
            const bool bn = (j0 + lb_n < N);
#pragma unroll
            for (int q = 0; q < 8; ++q) {
                int r = la_r + 8 * q;
                ra[q] = (k0 + 32 + la_c < K) ? A[(long)(i0 + r) * K + k0 + 32 + la_c] : 0.f;
                int kk = k0 + 32 + lb_k + 4 * q;
                rb[q] = (kk < K && bn) ? B[(long)kk * N + j0 + lb_n] : 0.f;
            }
        }
#pragma unroll
        for (int kk = 0; kk < 32; ++kk) {
            float4 a4 = *(const float4*)&As[kk][ty * 4];
            float4 b4 = *(const float4*)&Bs[kk][tx * 4];
            float av[4] = {a4.x, a4.y, a4.z, a4.w};
            float bv[4] = {b4.x, b4.y, b4.z, b4.w};
#pragma unroll
            for (int ii = 0; ii < 4; ++ii)
#pragma unroll
                for (int jj = 0; jj < 4; ++jj)
                    acc[ii][jj] = fmaf(av[ii], bv[jj], acc[ii][jj]);
        }
        __syncthreads();
    }

#pragma unroll
    for (int ii = 0; ii < 4; ++ii) {
        int i = i0 + ty * 4 + ii;
#pragma unroll
        for (int jj = 0; jj < 4; ++jj) {
            int j = j0 + tx * 4 + jj;
            if (j < N) {
                float v = acc[ii][jj] + bias[j];
                if (RELU) v = fmaxf(v, 0.f);
                Cm[(long)i * N + j] = v;
            }
        }
    }
}

// ---------------- log_softmax over 40 cols, wave per row, in place ----------------
__global__ void logsoftmax_kernel(float* __restrict__ out) {
    const int lane = threadIdx.x & 63;
    const int wid = threadIdx.x >> 6;
    const int row = blockIdx.x * 4 + wid;
    float* o = out + (long)row * 40;
    float v = (lane < 40) ? o[lane] : -INFINITY;
    float m = v;
#pragma unroll
    for (int off = 1; off < 64; off <<= 1) m = fmaxf(m, __shfl_xor(m, off));
    float e = (lane < 40) ? expf(v - m) : 0.f;
    float s = e;
#pragma unroll
    for (int off = 1; off < 64; off <<= 1) s += __shfl_xor(s, off);
    float r = (v - m) - logf(s);
    if (lane < 40) o[lane] = r;
}

extern "C" void kernel_launch(void* const* d_in, const int* in_sizes, int n_in,
                              void* d_out, int out_size, void* d_ws, size_t ws_size,
                              hipStream_t stream) {
    (void)in_sizes; (void)n_in; (void)out_size;
    const float* x     = (const float*)d_in[0];
    const float* w1    = (const float*)d_in[1];
    const float* w2    = (const float*)d_in[2];
    const float* w3    = (const float*)d_in[3];
    const float* lin1w = (const float*)d_in[4];
    const float* lin1b = (const float*)d_in[5];
    const float* wa    = (const float*)d_in[6];
    const float* ba    = (const float*)d_in[7];
    const float* wb    = (const float*)d_in[8];
    const float* bb    = (const float*)d_in[9];
    const float* wo    = (const float*)d_in[10];
    const float* bo    = (const float*)d_in[11];
    float* outp = (float*)d_out;

    // ---- ws_size-adaptive layout ----
    char* ws = (char*)d_ws;
    size_t off = 0;
    auto take = [&](size_t bytes) { char* p = ws + off; off += (bytes + 255) & ~(size_t)255; return p; };
    float* x2  = (float*)take((size_t)NPTS * 4);
    int*   idx = (int*)  take((size_t)NPTS * KNN * 4);
    float* h0  = (float*)take((size_t)NPTS * 420 * 4);
    float* sx0 = (float*)take((size_t)NPTS * 4);
    float* sx1 = (float*)take((size_t)NPTS * 4);
    float* sx2 = (float*)take((size_t)NPTS * 4);
    size_t rest = (ws_size > off) ? (ws_size - off) : 0;
    char*  scratch = ws + off;

    int cr = (int)(rest / ((size_t)NPTS * 4));   // fp32 dist chunk rows
    if (cr > 4096) cr = 4096;                    // 128 MB chunk: topk re-read stays L3-resident
    cr &= ~127;
    if (cr < 128) cr = 128;
    float* dist = (float*)scratch;

    int mr = (int)(rest / 5632);                 // fp32 MLP chunk rows
    if (mr > NPTS) mr = NPTS;
    mr &= ~127;
    if (mr < 128) mr = 128;

    dim3 b256(256);
    dim3 b512(NT);
    dim3 grow(NPTS);

    // ---- stage 1: fused knn(x, C=3) -> erode -> x1 = h0[:, 0:60]
    rowsq_np_kernel<3><<<dim3(32), b256, 0, stream>>>(x, 3, x2);
    soa3_kernel<<<dim3(32), b256, 0, stream>>>(x, sx0, sx1, sx2);
    knn3_fused_kernel<<<grow, b512, 0, stream>>>(sx0, sx1, sx2, x2, idx);
    erode_kernel<20, 3><<<grow, dim3(64), 0, stream>>>(x, 3, idx, w1, h0 + 0, 420);

    // ---- stage 2: knn(x1, C=60) -> erode -> x2f = h0[:, 60:180]
    rowsq_np_kernel<60><<<dim3(32), b256, 0, stream>>>(h0, 420, x2);
    for (int r0 = 0; r0 < NPTS; r0 += cr) {
        int rows = (NPTS - r0 < cr) ? (NPTS - r0) : cr;
        dist128_kernel<<<dim3(64, rows / 128), b256, 0, stream>>>(h0, 420, 60, x2, dist, r0);
        topk_kernel<<<dim3(rows), b512, 0, stream>>>(dist, idx, r0);
    }
    erode_kernel<2, 60><<<grow, dim3(128), 0, stream>>>(h0, 420, idx, w2, h0 + 60, 420);

    // ---- stage 3: knn(x2f, C=120) -> erode -> x3 = h0[:, 180:420]
    rowsq_np_kernel<120><<<dim3(32), b256, 0, stream>>>(h0 + 60, 420, x2);
    for (int r0 = 0; r0 < NPTS; r0 += cr) {
        int rows = (NPTS - r0 < cr) ? (NPTS - r0) : cr;
        dist128_kernel<<<dim3(64, rows / 128), b256, 0, stream>>>(h0 + 60, 420, 120, x2, dist, r0);
        topk_kernel<<<dim3(rows), b512, 0, stream>>>(dist, idx, r0);
    }
    erode_kernel<2, 120><<<grow, dim3(256), 0, stream>>>(h0 + 60, 420, idx, w3, h0 + 180, 420);

    // ---- MLP (row-chunked; h1|h2|h3 live in scratch)
    for (int r0 = 0; r0 < NPTS; r0 += mr) {
        int rows = (NPTS - r0 < mr) ? (NPTS - r0) : mr;
        float* h1c = (float*)scratch;
        float* h2c = h1c + (size_t)mr * 1024;
        float* h3c = h2c + (size_t)mr * 256;
        gemm128_kernel<1><<<dim3(8, rows / 128), b256, 0, stream>>>(h0 + (long)r0 * 420, lin1w, lin1b, h1c, 420, 1024);
        gemm_kernel<1><<<dim3(4, rows / 64), b256, 0, stream>>>(h1c, wa, ba, h2c, 1024, 256);
        gemm_kernel<1><<<dim3(2, rows / 64), b256, 0, stream>>>(h2c, wb, bb, h3c, 256, 128);
        gemm_kernel<0><<<dim3(1, rows / 64), b256, 0, stream>>>(h3c, wo, bo, outp + (long)r0 * 40, 128, 40);
        logsoftmax_kernel<<<dim3(rows / 4), b256, 0, stream>>>(outp + (long)r0 * 40);
    }
}

// Round 11
// 1024.469 us; speedup vs baseline: 1.4491x; 1.0165x over previous
//
#include <hip/hip_runtime.h>
#include <math.h>

#define NPTS 8192
#define KNN 20
#define CAP 256
#define NT 512               // threads for select kernels
#define MK (NPTS / NT)       // 16 keys per thread (registers)
#define NW (NT / 64)         // 8 waves

static __device__ __forceinline__ unsigned long long umin64(unsigned long long a, unsigned long long b) {
    return a < b ? a : b;
}
static __device__ __forceinline__ unsigned umin32(unsigned a, unsigned b) { return a < b ? a : b; }

// ---------------- row squared norms: bit-faithful replica of np.sum(x*x, -1) ----------------
template<int C>
__global__ void rowsq_np_kernel(const float* __restrict__ X, int ld, float* __restrict__ x2) {
#pragma clang fp contract(off)
    int i = blockIdx.x * blockDim.x + threadIdx.x;
    if (i >= NPTS) return;
    const float* row = X + (long)i * ld;
    float res;
    if (C < 8) {
        res = 0.f;
        for (int c = 0; c < C; ++c) res += row[c] * row[c];
    } else {
        float r[8];
#pragma unroll
        for (int j = 0; j < 8; ++j) r[j] = row[j] * row[j];
        int p = 8;
        for (; p < C - (C % 8); p += 8)
#pragma unroll
            for (int j = 0; j < 8; ++j) r[j] += row[p + j] * row[p + j];
        res = ((r[0] + r[1]) + (r[2] + r[3])) + ((r[4] + r[5]) + (r[6] + r[7]));
        for (; p < C; ++p) res += row[p] * row[p];
    }
    x2[i] = res;
}

// ---------------- X -> SoA (C=3) ----------------
__global__ void soa3_kernel(const float* __restrict__ X, float* __restrict__ X0,
                            float* __restrict__ X1, float* __restrict__ X2) {
    int i = blockIdx.x * blockDim.x + threadIdx.x;
    if (i < NPTS) { X0[i] = X[3 * i]; X1[i] = X[3 * i + 1]; X2[i] = X[3 * i + 2]; }
}

// ---------------- register-resident count of keys <= B ----------------
__device__ __forceinline__ int count_le_reg(const unsigned* k, unsigned B, int* scal) {
    const int tid = threadIdx.x;
    int cnt = 0;
#pragma unroll
    for (int m = 0; m < MK; ++m) cnt += (k[m] <= B) ? 1 : 0;
#pragma unroll
    for (int o = 32; o >= 1; o >>= 1) cnt += __shfl_down(cnt, (unsigned)o);
    if ((tid & 63) == 0) scal[tid >> 6] = cnt;
    __syncthreads();
    int tot = 0;
#pragma unroll
    for (int w = 0; w < NW; ++w) tot += scal[w];
    __syncthreads();
    return tot;
}

// ---------------- exact top-K via min-scan sample threshold, keys in REGISTERS ----------------
__device__ __forceinline__ void select20_reg(unsigned* k, unsigned* ured,
                                             unsigned long long* cand, int* scal,
                                             long row, int* __restrict__ idx_out) {
    const int tid = threadIdx.x;
    unsigned s = k[0];              // one sample per thread (j = tid)
    unsigned B; int c;
    for (;;) {
        unsigned m = s;
#pragma unroll
        for (int o = 32; o >= 1; o >>= 1) m = umin32(m, __shfl_down(m, (unsigned)o));
        if ((tid & 63) == 0) ured[tid >> 6] = m;
        __syncthreads();
        B = ured[0];
#pragma unroll
        for (int w = 1; w < NW; ++w) B = umin32(B, ured[w]);
        __syncthreads();
        c = count_le_reg(k, B, scal);
        if (c >= KNN) break;
        if (s <= B) s = 0xFFFFFFFFu;   // deactivate exhausted samples
    }
    if (tid == 0) scal[8] = 0;
    __syncthreads();

    if (c <= CAP) {
#pragma unroll
        for (int m = 0; m < MK; ++m) {
            if (k[m] <= B) {
                int j = tid + NT * m;
                int p = atomicAdd(&scal[8], 1);    // p < c <= CAP guaranteed
                cand[p] = (((unsigned long long)k[m]) << 32) | (unsigned)j;
            }
        }
        __syncthreads();
        const int nc = scal[8];
        if (tid < 64) {
            unsigned long long cc[4];
#pragma unroll
            for (int q = 0; q < 4; ++q) { int i = tid + 64 * q; cc[q] = (i < nc) ? cand[i] : ~0ull; }
            for (int it = 0; it < KNN; ++it) {
                unsigned long long g = umin64(umin64(cc[0], cc[1]), umin64(cc[2], cc[3]));
#pragma unroll
                for (int o = 1; o < 64; o <<= 1) g = umin64(g, __shfl_xor(g, o));
                if (tid == 0) idx_out[row * KNN + it] = (int)(unsigned)(g & 0xFFFFFFFFull);
#pragma unroll
                for (int q = 0; q < 4; ++q) if (cc[q] == g) cc[q] = ~0ull;
            }
        }
    } else {
        // exact fallback (massive ties) — not expected; cand[0..NW) reused as partials
        for (int it = 0; it < KNN; ++it) {
            unsigned long long best = ~0ull;
#pragma unroll
            for (int m = 0; m < MK; ++m)
                best = umin64(best, (((unsigned long long)k[m]) << 32) | (unsigned)(tid + NT * m));
#pragma unroll
            for (int o = 1; o < 64; o <<= 1) best = umin64(best, __shfl_xor(best, o));
            if ((tid & 63) == 0) cand[tid >> 6] = best;
            __syncthreads();
            unsigned long long g = cand[0];
#pragma unroll
            for (int w = 1; w < NW; ++w) g = umin64(g, cand[w]);
            int j = (int)(unsigned)(g & 0xFFFFFFFFull);
            if (tid == 0) idx_out[row * KNN + it] = j;
            __syncthreads();
            int mi = j / NT;
#pragma unroll
            for (int m = 0; m < MK; ++m)
                if (m == mi && tid == (j & (NT - 1))) k[m] = 0xFFFFFFFFu;
            __syncthreads();
        }
    }
}

// ---------------- stage-1 fused: C=3 distances (SoA) + top-K, keys in registers ----------------
__global__ __launch_bounds__(NT) void knn3_fused_kernel(const float* __restrict__ X0,
                                                        const float* __restrict__ X1,
                                                        const float* __restrict__ X2,
                                                        const float* __restrict__ x2,
                                                        int* __restrict__ idx_out) {
    __shared__ unsigned ured[NW];
    __shared__ unsigned long long cand[CAP];
    __shared__ int scal[16];
    unsigned k[MK];
    const int tid = threadIdx.x;
    const int row = blockIdx.x;
    const float xi0 = X0[row], xi1 = X1[row], xi2 = X2[row];
    const float x2i = x2[row];

#pragma unroll
    for (int m = 0; m < MK; ++m) {
        int j = tid + NT * m;
        float accv = 0.f;                       // identical ascending-c fmaf chain
        accv = fmaf(xi0, X0[j], accv);
        accv = fmaf(xi1, X1[j], accv);
        accv = fmaf(xi2, X2[j], accv);
        float d = (x2i + x2[j]) - 2.f * accv;
        unsigned u = __float_as_uint(d);
        k[m] = (u & 0x80000000u) ? ~u : (u | 0x80000000u);
    }
    select20_reg(k, ured, cand, scal, row, idx_out);
}

// ---------------- top-K from materialized dist rows, keys in registers ----------------
__global__ __launch_bounds__(NT) void topk_kernel(const float* __restrict__ dist, int* __restrict__ idx_out,
                                                  int rowbase) {
    __shared__ unsigned ured[NW];
    __shared__ unsigned long long cand[CAP];
    __shared__ int scal[16];
    unsigned k[MK];
    const int tid = threadIdx.x;
    const long row = rowbase + blockIdx.x;
    const float* drow = dist + (long)blockIdx.x * NPTS;

#pragma unroll
    for (int m = 0; m < MK; ++m) {
        unsigned u = __float_as_uint(drow[tid + NT * m]);
        k[m] = (u & 0x80000000u) ? ~u : (u | 0x80000000u);
    }
    select20_reg(k, ured, cand, scal, row, idx_out);
}

// ---------------- pairwise distance (fp32), 128x128 tile, 8x8 microtile, BK=16 prefetch ----------------
// Microtile ownership: rows ty*4+{0..3} U ty*4+64+{0..3}; cols tx*4+{0..3} U tx*4+64+{0..3}.
// All LDS fragment reads sit on 16B stride -> 2-way bank aliasing (free on gfx950).
// Bit-exact: each element keeps its own ascending-k fmaf chain.
__global__ __launch_bounds__(256) void dist128_kernel(const float* __restrict__ X, int ld, int C,
                                                      const float* __restrict__ x2,
                                                      float* __restrict__ dist, int i0base) {
    __shared__ float As[16][132];
    __shared__ float Bs[16][132];
    const int tid = threadIdx.x;
    const int i0 = i0base + blockIdx.y * 128;
    const int j0 = blockIdx.x * 128;
    const int ty = tid >> 4, tx = tid & 15;
    const int lc = tid & 15, lr = tid >> 4;

    float ra[8], rb[8];
    float acc[8][8];   // acc[v*4+rr][u*4+cc]: row ty*4+64v+rr, col tx*4+64u+cc
#pragma unroll
    for (int a = 0; a < 8; ++a)
#pragma unroll
        for (int b = 0; b < 8; ++b) acc[a][b] = 0.f;

    {
        const bool v = (lc < C);
#pragma unroll
        for (int q = 0; q < 8; ++q) {
            int r = lr + 16 * q;
            ra[q] = v ? X[(long)(i0 + r) * ld + lc] : 0.f;
            rb[q] = v ? X[(long)(j0 + r) * ld + lc] : 0.f;
        }
    }

    for (int k0 = 0; k0 < C; k0 += 16) {
#pragma unroll
        for (int q = 0; q < 8; ++q) {
            As[lc][lr + 16 * q] = ra[q];
            Bs[lc][lr + 16 * q] = rb[q];
        }
        __syncthreads();
        if (k0 + 16 < C) {
            const bool v = (k0 + 16 + lc < C);
#pragma unroll
            for (int q = 0; q < 8; ++q) {
                int r = lr + 16 * q;
                ra[q] = v ? X[(long)(i0 + r) * ld + k0 + 16 + lc] : 0.f;
                rb[q] = v ? X[(long)(j0 + r) * ld + k0 + 16 + lc] : 0.f;
            }
        }
#pragma unroll
        for (int kk = 0; kk < 16; ++kk) {
            float4 a0 = *(const float4*)&As[kk][ty * 4];
            float4 a1 = *(const float4*)&As[kk][ty * 4 + 64];
            float4 b0 = *(const float4*)&Bs[kk][tx * 4];
            float4 b1 = *(const float4*)&Bs[kk][tx * 4 + 64];
            float av[8] = {a0.x, a0.y, a0.z, a0.w, a1.x, a1.y, a1.z, a1.w};
            float bv[8] = {b0.x, b0.y, b0.z, b0.w, b1.x, b1.y, b1.z, b1.w};
#pragma unroll
            for (int ii = 0; ii < 8; ++ii)
#pragma unroll
                for (int jj = 0; jj < 8; ++jj)
                    acc[ii][jj] = fmaf(av[ii], bv[jj], acc[ii][jj]);
        }
        __syncthreads();
    }

    float xj[8];
#pragma unroll
    for (int u = 0; u < 2; ++u)
#pragma unroll
        for (int cc = 0; cc < 4; ++cc) xj[u * 4 + cc] = x2[j0 + tx * 4 + 64 * u + cc];
#pragma unroll
    for (int v = 0; v < 2; ++v) {
#pragma unroll
        for (int rr = 0; rr < 4; ++rr) {
            int rloc = blockIdx.y * 128 + ty * 4 + 64 * v + rr;
            float xi = x2[i0base + rloc];
            int ii = v * 4 + rr;
#pragma unroll
            for (int u = 0; u < 2; ++u) {
                float4 o;
                o.x = (xi + xj[u * 4 + 0]) - 2.f * acc[ii][u * 4 + 0];
                o.y = (xi + xj[u * 4 + 1]) - 2.f * acc[ii][u * 4 + 1];
                o.z = (xi + xj[u * 4 + 2]) - 2.f * acc[ii][u * 4 + 2];
                o.w = (xi + xj[u * 4 + 3]) - 2.f * acc[ii][u * 4 + 3];
                *(float4*)&dist[(long)rloc * NPTS + j0 + tx * 4 + 64 * u] = o;
            }
        }
    }
}

// ---------------- erosion edge-conv (fp32, order-free exact) ----------------
template<int F, int C>
__global__ void erode_kernel(const float* __restrict__ X, int ld, const int* __restrict__ idx,
                             const float* __restrict__ w, float* __restrict__ out, int ldo) {
    __shared__ int nidx[KNN];
    __shared__ float neigh[KNN * C];
    const int tid = threadIdx.x;
    const int row = blockIdx.x;
    if (tid < KNN) nidx[tid] = idx[row * KNN + tid];
    __syncthreads();
    for (int t = tid; t < KNN * C; t += blockDim.x) {
        int k = t / C, c = t % C;
        neigh[t] = X[(long)nidx[k] * ld + c];
    }
    __syncthreads();
    if (tid < F * C) {
        int f = tid / C, c = tid % C;
        float m = neigh[c] - w[f * KNN * C + c];
        for (int k = 1; k < KNN; ++k)
            m = fminf(m, neigh[k * C + c] - w[(f * KNN + k) * C + c]);
        out[(long)row * ldo + tid] = m;
    }
}

// ---------------- fp32 GEMM 128x128 (lin1), BK=16 prefetch, bias+ReLU ----------------
// Same 2-way-free microtile mapping as dist128.
template<int RELU>
__global__ __launch_bounds__(256) void gemm128_kernel(const float* __restrict__ A, const float* __restrict__ B,
                                                      const float* __restrict__ bias, float* __restrict__ Cm,
                                                      int K, int N) {
    __shared__ float As[16][132];
    __shared__ float Bs[16][132];
    const int tid = threadIdx.x;
    const int i0 = blockIdx.y * 128, j0 = blockIdx.x * 128;
    const int ty = tid >> 4, tx = tid & 15;
    const int lc = tid & 15, lr = tid >> 4;
    const int lb_n = tid & 127, lb_k = tid >> 7;

    float ra[8], rb[8];
    float acc[8][8];
#pragma unroll
    for (int a = 0; a < 8; ++a)
#pragma unroll
        for (int b = 0; b < 8; ++b) acc[a][b] = 0.f;

    {
        const bool bn = (j0 + lb_n < N);
#pragma unroll
        for (int q = 0; q < 8; ++q) {
            int r = lr + 16 * q;
            ra[q] = (lc < K) ? A[(long)(i0 + r) * K + lc] : 0.f;
            int kk = lb_k + 2 * q;
            rb[q] = (kk < K && bn) ? B[(long)kk * N + j0 + lb_n] : 0.f;
        }
    }

    for (int k0 = 0; k0 < K; k0 += 16) {
#pragma unroll
        for (int q = 0; q < 8; ++q) {
            As[lc][lr + 16 * q] = ra[q];
            Bs[lb_k + 2 * q][lb_n] = rb[q];
        }
        __syncthreads();
        if (k0 + 16 < K) {
            const bool bn = (j0 + lb_n < N);
#pragma unroll
            for (int q = 0; q < 8; ++q) {
                int r = lr + 16 * q;
                ra[q] = (k0 + 16 + lc < K) ? A[(long)(i0 + r) * K + k0 + 16 + lc] : 0.f;
                int kk = k0 + 16 + lb_k + 2 * q;
                rb[q] = (kk < K && bn) ? B[(long)kk * N + j0 + lb_n] : 0.f;
            }
        }
#pragma unroll
        for (int kk = 0; kk < 16; ++kk) {
            float4 a0 = *(const float4*)&As[kk][ty * 4];
            float4 a1 = *(const float4*)&As[kk][ty * 4 + 64];
            float4 b0 = *(const float4*)&Bs[kk][tx * 4];
            float4 b1 = *(const float4*)&Bs[kk][tx * 4 + 64];
            float av[8] = {a0.x, a0.y, a0.z, a0.w, a1.x, a1.y, a1.z, a1.w};
            float bv[8] = {b0.x, b0.y, b0.z, b0.w, b1.x, b1.y, b1.z, b1.w};
#pragma unroll
            for (int ii = 0; ii < 8; ++ii)
#pragma unroll
                for (int jj = 0; jj < 8; ++jj)
                    acc[ii][jj] = fmaf(av[ii], bv[jj], acc[ii][jj]);
        }
        __syncthreads();
    }

#pragma unroll
    for (int v = 0; v < 2; ++v) {
#pragma unroll
        for (int rr = 0; rr < 4; ++rr) {
            int i = i0 + ty * 4 + 64 * v + rr;
            int ii = v * 4 + rr;
#pragma unroll
            for (int u = 0; u < 2; ++u) {
#pragma unroll
                for (int cc = 0; cc < 4; ++cc) {
                    int j = j0 + tx * 4 + 64 * u + cc;
                    if (j < N) {
                        float val = acc[ii][u * 4 + cc] + bias[j];
                        if (RELU) val = fmaxf(val, 0.f);
                        Cm[(long)i * N + j] = val;
                    }
                }
            }
        }
    }
}

// ---------------- fp32 GEMM 64x64 (layers 2-4), BK=32 prefetch ----------------
template<int RELU>
__global__ __launch_bounds__(256) void gemm_kernel(const float* __restrict__ A, const float* __restrict__ B,
                                                   const float* __restrict__ bias, float* __restrict__ Cm,
                                                   int K, int N) {
    __shared__ float As[32][68];
    __shared__ float Bs[32][68];
    const int tid = threadIdx.x;
    const int i0 = blockIdx.y * 64, j0 = blockIdx.x * 64;
    const int ty = tid >> 4, tx = tid & 15;
    const int la_c = tid & 31, la_r = tid >> 5;
    const int lb_n = tid & 63, lb_k = tid >> 6;

    float ra[8], rb[8];
    float acc[4][4];
#pragma unroll
    for (int a = 0; a < 4; ++a)
#pragma unroll
        for (int b = 0; b < 4; ++b) acc[a][b] = 0.f;

    {
        const bool bn = (j0 + lb_n < N);
#pragma unroll
        for (int q = 0; q < 8; ++q) {
            int r = la_r + 8 * q;
            ra[q] = (la_c < K) ? A[(long)(i0 + r) * K + la_c] : 0.f;
            int kk = lb_k + 4 * q;
            rb[q] = (kk < K && bn) ? B[(long)kk * N + j0 + lb_n] : 0.f;
        }
    }

    for (int k0 = 0; k0 < K; k0 += 32) {
#pragma unroll
        for (int q = 0; q < 8; ++q) {
            As[la_c][la_r + 8 * q] = ra[q];
            Bs[lb_k + 4 * q][lb_n] = rb[q];
        }
        __syncthreads();
        if (k0 + 32 < K) {
            const bool bn = (j0 + lb_n < N);
#pragma unroll
            for (int q = 0; q < 8; ++q) {
                int r = la_r + 8 * q;
                ra[q] = (k0 + 32 + la_c < K) ? A[(long)(i0 + r) * K + k0 + 32 + la_c] : 0.f;
                int kk = k0 + 32 + lb_k + 4 * q;
                rb[q] = (kk < K && bn) ? B[(long)kk * N + j0 + lb_n] : 0.f;
            }
        }
#pragma unroll
        for (int kk = 0; kk < 32; ++kk) {
            float4 a4 = *(const float4*)&As[kk][ty * 4];
            float4 b4 = *(const float4*)&Bs[kk][tx * 4];
            float av[4] = {a4.x, a4.y, a4.z, a4.w};
            float bv[4] = {b4.x, b4.y, b4.z, b4.w};
#pragma unroll
            for (int ii = 0; ii < 4; ++ii)
#pragma unroll
                for (int jj = 0; jj < 4; ++jj)
                    acc[ii][jj] = fmaf(av[ii], bv[jj], acc[ii][jj]);
        }
        __syncthreads();
    }

#pragma unroll
    for (int ii = 0; ii < 4; ++ii) {
        int i = i0 + ty * 4 + ii;
#pragma unroll
        for (int jj = 0; jj < 4; ++jj) {
            int j = j0 + tx * 4 + jj;
            if (j < N) {
                float v = acc[ii][jj] + bias[j];
                if (RELU) v = fmaxf(v, 0.f);
                Cm[(long)i * N + j] = v;
            }
        }
    }
}

// ---------------- log_softmax over 40 cols, wave per row, in place ----------------
__global__ void logsoftmax_kernel(float* __restrict__ out) {
    const int lane = threadIdx.x & 63;
    const int wid = threadIdx.x >> 6;
    const int row = blockIdx.x * 4 + wid;
    float* o = out + (long)row * 40;
    float v = (lane < 40) ? o[lane] : -INFINITY;
    float m = v;
#pragma unroll
    for (int off = 1; off < 64; off <<= 1) m = fmaxf(m, __shfl_xor(m, off));
    float e = (lane < 40) ? expf(v - m) : 0.f;
    float s = e;
#pragma unroll
    for (int off = 1; off < 64; off <<= 1) s += __shfl_xor(s, off);
    float r = (v - m) - logf(s);
    if (lane < 40) o[lane] = r;
}

extern "C" void kernel_launch(void* const* d_in, const int* in_sizes, int n_in,
                              void* d_out, int out_size, void* d_ws, size_t ws_size,
                              hipStream_t stream) {
    (void)in_sizes; (void)n_in; (void)out_size;
    const float* x     = (const float*)d_in[0];
    const float* w1    = (const float*)d_in[1];
    const float* w2    = (const float*)d_in[2];
    const float* w3    = (const float*)d_in[3];
    const float* lin1w = (const float*)d_in[4];
    const float* lin1b = (const float*)d_in[5];
    const float* wa    = (const float*)d_in[6];
    const float* ba    = (const float*)d_in[7];
    const float* wb    = (const float*)d_in[8];
    const float* bb    = (const float*)d_in[9];
    const float* wo    = (const float*)d_in[10];
    const float* bo    = (const float*)d_in[11];
    float* outp = (float*)d_out;

    // ---- ws_size-adaptive layout ----
    char* ws = (char*)d_ws;
    size_t off = 0;
    auto take = [&](size_t bytes) { char* p = ws + off; off += (bytes + 255) & ~(size_t)255; return p; };
    float* x2  = (float*)take((size_t)NPTS * 4);
    int*   idx = (int*)  take((size_t)NPTS * KNN * 4);
    float* h0  = (float*)take((size_t)NPTS * 420 * 4);
    float* sx0 = (float*)take((size_t)NPTS * 4);
    float* sx1 = (float*)take((size_t)NPTS * 4);
    float* sx2 = (float*)take((size_t)NPTS * 4);
    size_t rest = (ws_size > off) ? (ws_size - off) : 0;
    char*  scratch = ws + off;

    int cr = (int)(rest / ((size_t)NPTS * 4));   // fp32 dist chunk rows
    if (cr > 4096) cr = 4096;                    // 128 MB chunk: topk re-read stays L3-resident
    cr &= ~127;
    if (cr < 128) cr = 128;
    float* dist = (float*)scratch;

    int mr = (int)(rest / 5632);                 // fp32 MLP chunk rows
    if (mr > NPTS) mr = NPTS;
    mr &= ~127;
    if (mr < 128) mr = 128;

    dim3 b256(256);
    dim3 b512(NT);
    dim3 grow(NPTS);

    // ---- stage 1: fused knn(x, C=3) -> erode -> x1 = h0[:, 0:60]
    rowsq_np_kernel<3><<<dim3(32), b256, 0, stream>>>(x, 3, x2);
    soa3_kernel<<<dim3(32), b256, 0, stream>>>(x, sx0, sx1, sx2);
    knn3_fused_kernel<<<grow, b512, 0, stream>>>(sx0, sx1, sx2, x2, idx);
    erode_kernel<20, 3><<<grow, dim3(64), 0, stream>>>(x, 3, idx, w1, h0 + 0, 420);

    // ---- stage 2: knn(x1, C=60) -> erode -> x2f = h0[:, 60:180]
    rowsq_np_kernel<60><<<dim3(32), b256, 0, stream>>>(h0, 420, x2);
    for (int r0 = 0; r0 < NPTS; r0 += cr) {
        int rows = (NPTS - r0 < cr) ? (NPTS - r0) : cr;
        dist128_kernel<<<dim3(64, rows / 128), b256, 0, stream>>>(h0, 420, 60, x2, dist, r0);
        topk_kernel<<<dim3(rows), b512, 0, stream>>>(dist, idx, r0);
    }
    erode_kernel<2, 60><<<grow, dim3(128), 0, stream>>>(h0, 420, idx, w2, h0 + 60, 420);

    // ---- stage 3: knn(x2f, C=120) -> erode -> x3 = h0[:, 180:420]
    rowsq_np_kernel<120><<<dim3(32), b256, 0, stream>>>(h0 + 60, 420, x2);
    for (int r0 = 0; r0 < NPTS; r0 += cr) {
        int rows = (NPTS - r0 < cr) ? (NPTS - r0) : cr;
        dist128_kernel<<<dim3(64, rows / 128), b256, 0, stream>>>(h0 + 60, 420, 120, x2, dist, r0);
        topk_kernel<<<dim3(rows), b512, 0, stream>>>(dist, idx, r0);
    }
    erode_kernel<2, 120><<<grow, dim3(256), 0, stream>>>(h0 + 60, 420, idx, w3, h0 + 180, 420);

    // ---- MLP (row-chunked; h1|h2|h3 live in scratch)
    for (int r0 = 0; r0 < NPTS; r0 += mr) {
        int rows = (NPTS - r0 < mr) ? (NPTS - r0) : mr;
        float* h1c = (float*)scratch;
        float* h2c = h1c + (size_t)mr * 1024;
        float* h3c = h2c + (size_t)mr * 256;
        gemm128_kernel<1><<<dim3(8, rows / 128), b256, 0, stream>>>(h0 + (long)r0 * 420, lin1w, lin1b, h1c, 420, 1024);
        gemm_kernel<1><<<dim3(4, rows / 64), b256, 0, stream>>>(h1c, wa, ba, h2c, 1024, 256);
        gemm_kernel<1><<<dim3(2, rows / 64), b256, 0, stream>>>(h2c, wb, bb, h3c, 256, 128);
        gemm_kernel<0><<<dim3(1, rows / 64), b256, 0, stream>>>(h3c, wo, bo, outp + (long)r0 * 40, 128, 40);
        logsoftmax_kernel<<<dim3(rows / 4), b256, 0, stream>>>(outp + (long)r0 * 40);
    }
}

// Round 12
// 997.198 us; speedup vs baseline: 1.4887x; 1.0273x over previous
//
#include <hip/hip_runtime.h>
#include <math.h>

#define NPTS 8192
#define KNN 20
#define CAP 256
#define NT 512               // threads for select kernels
#define MK (NPTS / NT)       // 16 keys per thread (registers)
#define NW (NT / 64)         // 8 waves

static __device__ __forceinline__ unsigned long long umin64(unsigned long long a, unsigned long long b) {
    return a < b ? a : b;
}
static __device__ __forceinline__ unsigned umin32(unsigned a, unsigned b) { return a < b ? a : b; }

// ---------------- row squared norms: bit-faithful replica of np.sum(x*x, -1) ----------------
template<int C>
__global__ void rowsq_np_kernel(const float* __restrict__ X, int ld, float* __restrict__ x2) {
#pragma clang fp contract(off)
    int i = blockIdx.x * blockDim.x + threadIdx.x;
    if (i >= NPTS) return;
    const float* row = X + (long)i * ld;
    float res;
    if (C < 8) {
        res = 0.f;
        for (int c = 0; c < C; ++c) res += row[c] * row[c];
    } else {
        float r[8];
#pragma unroll
        for (int j = 0; j < 8; ++j) r[j] = row[j] * row[j];
        int p = 8;
        for (; p < C - (C % 8); p += 8)
#pragma unroll
            for (int j = 0; j < 8; ++j) r[j] += row[p + j] * row[p + j];
        res = ((r[0] + r[1]) + (r[2] + r[3])) + ((r[4] + r[5]) + (r[6] + r[7]));
        for (; p < C; ++p) res += row[p] * row[p];
    }
    x2[i] = res;
}

// ---------------- X -> SoA (C=3) ----------------
__global__ void soa3_kernel(const float* __restrict__ X, float* __restrict__ X0,
                            float* __restrict__ X1, float* __restrict__ X2) {
    int i = blockIdx.x * blockDim.x + threadIdx.x;
    if (i < NPTS) { X0[i] = X[3 * i]; X1[i] = X[3 * i + 1]; X2[i] = X[3 * i + 2]; }
}

// ---------------- slab transpose: X (row-major, ld) cols[0..C) -> XT[c][j] ----------------
// 32x32 LDS tile; exact value copy (bit-identical staging source for dist128).
__global__ __launch_bounds__(256) void transpose_kernel(const float* __restrict__ X, int ld, int C,
                                                        float* __restrict__ XT) {
    __shared__ float t[32][33];
    const int jb = blockIdx.x * 32;
    const int cb = blockIdx.y * 32;
    const int tx = threadIdx.x & 31, ty = threadIdx.x >> 5;
#pragma unroll
    for (int k = 0; k < 4; ++k) {
        int j = jb + ty + 8 * k;
        int c = cb + tx;
        t[ty + 8 * k][tx] = (c < C) ? X[(long)j * ld + c] : 0.f;
    }
    __syncthreads();
#pragma unroll
    for (int k = 0; k < 4; ++k) {
        int c = cb + ty + 8 * k;
        int j = jb + tx;
        if (c < C) XT[(long)c * NPTS + j] = t[tx][ty + 8 * k];
    }
}

// ---------------- register-resident count of keys <= B ----------------
__device__ __forceinline__ int count_le_reg(const unsigned* k, unsigned B, int* scal) {
    const int tid = threadIdx.x;
    int cnt = 0;
#pragma unroll
    for (int m = 0; m < MK; ++m) cnt += (k[m] <= B) ? 1 : 0;
#pragma unroll
    for (int o = 32; o >= 1; o >>= 1) cnt += __shfl_down(cnt, (unsigned)o);
    if ((tid & 63) == 0) scal[tid >> 6] = cnt;
    __syncthreads();
    int tot = 0;
#pragma unroll
    for (int w = 0; w < NW; ++w) tot += scal[w];
    __syncthreads();
    return tot;
}

// ---------------- exact top-K via min-scan sample threshold, keys in REGISTERS ----------------
__device__ __forceinline__ void select20_reg(unsigned* k, unsigned* ured,
                                             unsigned long long* cand, int* scal,
                                             long row, int* __restrict__ idx_out) {
    const int tid = threadIdx.x;
    unsigned s = k[0];              // one sample per thread (j = tid)
    unsigned B; int c;
    for (;;) {
        unsigned m = s;
#pragma unroll
        for (int o = 32; o >= 1; o >>= 1) m = umin32(m, __shfl_down(m, (unsigned)o));
        if ((tid & 63) == 0) ured[tid >> 6] = m;
        __syncthreads();
        B = ured[0];
#pragma unroll
        for (int w = 1; w < NW; ++w) B = umin32(B, ured[w]);
        __syncthreads();
        c = count_le_reg(k, B, scal);
        if (c >= KNN) break;
        if (s <= B) s = 0xFFFFFFFFu;   // deactivate exhausted samples
    }
    if (tid == 0) scal[8] = 0;
    __syncthreads();

    if (c <= CAP) {
#pragma unroll
        for (int m = 0; m < MK; ++m) {
            if (k[m] <= B) {
                int j = tid + NT * m;
                int p = atomicAdd(&scal[8], 1);    // p < c <= CAP guaranteed
                cand[p] = (((unsigned long long)k[m]) << 32) | (unsigned)j;
            }
        }
        __syncthreads();
        const int nc = scal[8];
        if (tid < 64) {
            unsigned long long cc[4];
#pragma unroll
            for (int q = 0; q < 4; ++q) { int i = tid + 64 * q; cc[q] = (i < nc) ? cand[i] : ~0ull; }
            for (int it = 0; it < KNN; ++it) {
                unsigned long long g = umin64(umin64(cc[0], cc[1]), umin64(cc[2], cc[3]));
#pragma unroll
                for (int o = 1; o < 64; o <<= 1) g = umin64(g, __shfl_xor(g, o));
                if (tid == 0) idx_out[row * KNN + it] = (int)(unsigned)(g & 0xFFFFFFFFull);
#pragma unroll
                for (int q = 0; q < 4; ++q) if (cc[q] == g) cc[q] = ~0ull;
            }
        }
    } else {
        // exact fallback (massive ties) — not expected; cand[0..NW) reused as partials
        for (int it = 0; it < KNN; ++it) {
            unsigned long long best = ~0ull;
#pragma unroll
            for (int m = 0; m < MK; ++m)
                best = umin64(best, (((unsigned long long)k[m]) << 32) | (unsigned)(tid + NT * m));
#pragma unroll
            for (int o = 1; o < 64; o <<= 1) best = umin64(best, __shfl_xor(best, o));
            if ((tid & 63) == 0) cand[tid >> 6] = best;
            __syncthreads();
            unsigned long long g = cand[0];
#pragma unroll
            for (int w = 1; w < NW; ++w) g = umin64(g, cand[w]);
            int j = (int)(unsigned)(g & 0xFFFFFFFFull);
            if (tid == 0) idx_out[row * KNN + it] = j;
            __syncthreads();
            int mi = j / NT;
#pragma unroll
            for (int m = 0; m < MK; ++m)
                if (m == mi && tid == (j & (NT - 1))) k[m] = 0xFFFFFFFFu;
            __syncthreads();
        }
    }
}

// ---------------- stage-1 fused: C=3 distances (SoA) + top-K, keys in registers ----------------
__global__ __launch_bounds__(NT) void knn3_fused_kernel(const float* __restrict__ X0,
                                                        const float* __restrict__ X1,
                                                        const float* __restrict__ X2,
                                                        const float* __restrict__ x2,
                                                        int* __restrict__ idx_out) {
    __shared__ unsigned ured[NW];
    __shared__ unsigned long long cand[CAP];
    __shared__ int scal[16];
    unsigned k[MK];
    const int tid = threadIdx.x;
    const int row = blockIdx.x;
    const float xi0 = X0[row], xi1 = X1[row], xi2 = X2[row];
    const float x2i = x2[row];

#pragma unroll
    for (int m = 0; m < MK; ++m) {
        int j = tid + NT * m;
        float accv = 0.f;                       // identical ascending-c fmaf chain
        accv = fmaf(xi0, X0[j], accv);
        accv = fmaf(xi1, X1[j], accv);
        accv = fmaf(xi2, X2[j], accv);
        float d = (x2i + x2[j]) - 2.f * accv;
        unsigned u = __float_as_uint(d);
        k[m] = (u & 0x80000000u) ? ~u : (u | 0x80000000u);
    }
    select20_reg(k, ured, cand, scal, row, idx_out);
}

// ---------------- top-K from materialized dist rows, keys in registers ----------------
__global__ __launch_bounds__(NT) void topk_kernel(const float* __restrict__ dist, int* __restrict__ idx_out,
                                                  int rowbase) {
    __shared__ unsigned ured[NW];
    __shared__ unsigned long long cand[CAP];
    __shared__ int scal[16];
    unsigned k[MK];
    const int tid = threadIdx.x;
    const long row = rowbase + blockIdx.x;
    const float* drow = dist + (long)blockIdx.x * NPTS;

#pragma unroll
    for (int m = 0; m < MK; ++m) {
        unsigned u = __float_as_uint(drow[tid + NT * m]);
        k[m] = (u & 0x80000000u) ? ~u : (u | 0x80000000u);
    }
    select20_reg(k, ured, cand, scal, row, idx_out);
}

// ---------------- pairwise distance (fp32), 128x128 tile, 8x8 microtile, BK=16 prefetch ----------------
// Staging from transposed slab XT[c][j]: float4 coalesced global loads + b128 LDS writes.
// Microtile: rows ty*4+{0..3} U +64; cols tx*4+{0..3} U +64 (16B-stride LDS reads, 2-way = free).
// Bit-exact: per-element ascending-k fmaf chains and epilogue unchanged.
__global__ __launch_bounds__(256) void dist128_kernel(const float* __restrict__ XT, int C,
                                                      const float* __restrict__ x2,
                                                      float* __restrict__ dist, int i0base) {
    __shared__ float As[16][132];
    __shared__ float Bs[16][132];
    const int tid = threadIdx.x;
    const int i0 = i0base + blockIdx.y * 128;
    const int j0 = blockIdx.x * 128;
    const int ty = tid >> 4, tx = tid & 15;
    const int lc = tid >> 5;            // loader col 0..7 (and +8)
    const int lr4 = (tid & 31) * 4;     // loader row group

    const float4 z4 = {0.f, 0.f, 0.f, 0.f};
    float4 ra0, ra1, rb0, rb1;
    float acc[8][8];
#pragma unroll
    for (int a = 0; a < 8; ++a)
#pragma unroll
        for (int b = 0; b < 8; ++b) acc[a][b] = 0.f;

    {
        const bool v0 = (lc < C), v1 = (lc + 8 < C);
        ra0 = v0 ? *(const float4*)&XT[(long)lc * NPTS + i0 + lr4] : z4;
        ra1 = v1 ? *(const float4*)&XT[(long)(lc + 8) * NPTS + i0 + lr4] : z4;
        rb0 = v0 ? *(const float4*)&XT[(long)lc * NPTS + j0 + lr4] : z4;
        rb1 = v1 ? *(const float4*)&XT[(long)(lc + 8) * NPTS + j0 + lr4] : z4;
    }

    for (int k0 = 0; k0 < C; k0 += 16) {
        *(float4*)&As[lc][lr4]     = ra0;
        *(float4*)&As[lc + 8][lr4] = ra1;
        *(float4*)&Bs[lc][lr4]     = rb0;
        *(float4*)&Bs[lc + 8][lr4] = rb1;
        __syncthreads();
        if (k0 + 16 < C) {
            const int c0 = k0 + 16 + lc, c1 = c0 + 8;
            const bool v0 = (c0 < C), v1 = (c1 < C);
            ra0 = v0 ? *(const float4*)&XT[(long)c0 * NPTS + i0 + lr4] : z4;
            ra1 = v1 ? *(const float4*)&XT[(long)c1 * NPTS + i0 + lr4] : z4;
            rb0 = v0 ? *(const float4*)&XT[(long)c0 * NPTS + j0 + lr4] : z4;
            rb1 = v1 ? *(const float4*)&XT[(long)c1 * NPTS + j0 + lr4] : z4;
        }
#pragma unroll
        for (int kk = 0; kk < 16; ++kk) {
            float4 a0 = *(const float4*)&As[kk][ty * 4];
            float4 a1 = *(const float4*)&As[kk][ty * 4 + 64];
            float4 b0 = *(const float4*)&Bs[kk][tx * 4];
            float4 b1 = *(const float4*)&Bs[kk][tx * 4 + 64];
            float av[8] = {a0.x, a0.y, a0.z, a0.w, a1.x, a1.y, a1.z, a1.w};
            float bv[8] = {b0.x, b0.y, b0.z, b0.w, b1.x, b1.y, b1.z, b1.w};
#pragma unroll
            for (int ii = 0; ii < 8; ++ii)
#pragma unroll
                for (int jj = 0; jj < 8; ++jj)
                    acc[ii][jj] = fmaf(av[ii], bv[jj], acc[ii][jj]);
        }
        __syncthreads();
    }

    float xj[8];
#pragma unroll
    for (int u = 0; u < 2; ++u)
#pragma unroll
        for (int cc = 0; cc < 4; ++cc) xj[u * 4 + cc] = x2[j0 + tx * 4 + 64 * u + cc];
#pragma unroll
    for (int v = 0; v < 2; ++v) {
#pragma unroll
        for (int rr = 0; rr < 4; ++rr) {
            int rloc = blockIdx.y * 128 + ty * 4 + 64 * v + rr;
            float xi = x2[i0base + rloc];
            int ii = v * 4 + rr;
#pragma unroll
            for (int u = 0; u < 2; ++u) {
                float4 o;
                o.x = (xi + xj[u * 4 + 0]) - 2.f * acc[ii][u * 4 + 0];
                o.y = (xi + xj[u * 4 + 1]) - 2.f * acc[ii][u * 4 + 1];
                o.z = (xi + xj[u * 4 + 2]) - 2.f * acc[ii][u * 4 + 2];
                o.w = (xi + xj[u * 4 + 3]) - 2.f * acc[ii][u * 4 + 3];
                *(float4*)&dist[(long)rloc * NPTS + j0 + tx * 4 + 64 * u] = o;
            }
        }
    }
}

// ---------------- erosion edge-conv (fp32, order-free exact) ----------------
template<int F, int C>
__global__ void erode_kernel(const float* __restrict__ X, int ld, const int* __restrict__ idx,
                             const float* __restrict__ w, float* __restrict__ out, int ldo) {
    __shared__ int nidx[KNN];
    __shared__ float neigh[KNN * C];
    const int tid = threadIdx.x;
    const int row = blockIdx.x;
    if (tid < KNN) nidx[tid] = idx[row * KNN + tid];
    __syncthreads();
    for (int t = tid; t < KNN * C; t += blockDim.x) {
        int k = t / C, c = t % C;
        neigh[t] = X[(long)nidx[k] * ld + c];
    }
    __syncthreads();
    if (tid < F * C) {
        int f = tid / C, c = tid % C;
        float m = neigh[c] - w[f * KNN * C + c];
        for (int k = 1; k < KNN; ++k)
            m = fminf(m, neigh[k * C + c] - w[(f * KNN + k) * C + c]);
        out[(long)row * ldo + tid] = m;
    }
}

// ---------------- fp32 GEMM 128x128 (lin1), BK=16 prefetch, bias+ReLU ----------------
template<int RELU>
__global__ __launch_bounds__(256) void gemm128_kernel(const float* __restrict__ A, const float* __restrict__ B,
                                                      const float* __restrict__ bias, float* __restrict__ Cm,
                                                      int K, int N) {
    __shared__ float As[16][132];
    __shared__ float Bs[16][132];
    const int tid = threadIdx.x;
    const int i0 = blockIdx.y * 128, j0 = blockIdx.x * 128;
    const int ty = tid >> 4, tx = tid & 15;
    const int lc = tid & 15, lr = tid >> 4;
    const int lb_n = tid & 127, lb_k = tid >> 7;

    float ra[8], rb[8];
    float acc[8][8];
#pragma unroll
    for (int a = 0; a < 8; ++a)
#pragma unroll
        for (int b = 0; b < 8; ++b) acc[a][b] = 0.f;

    {
        const bool bn = (j0 + lb_n < N);
#pragma unroll
        for (int q = 0; q < 8; ++q) {
            int r = lr + 16 * q;
            ra[q] = (lc < K) ? A[(long)(i0 + r) * K + lc] : 0.f;
            int kk = lb_k + 2 * q;
            rb[q] = (kk < K && bn) ? B[(long)kk * N + j0 + lb_n] : 0.f;
        }
    }

    for (int k0 = 0; k0 < K; k0 += 16) {
#pragma unroll
        for (int q = 0; q < 8; ++q) {
            As[lc][lr + 16 * q] = ra[q];
            Bs[lb_k + 2 * q][lb_n] = rb[q];
        }
        __syncthreads();
        if (k0 + 16 < K) {
            const bool bn = (j0 + lb_n < N);
#pragma unroll
            for (int q = 0; q < 8; ++q) {
                int r = lr + 16 * q;
                ra[q] = (k0 + 16 + lc < K) ? A[(long)(i0 + r) * K + k0 + 16 + lc] : 0.f;
                int kk = k0 + 16 + lb_k + 2 * q;
                rb[q] = (kk < K && bn) ? B[(long)kk * N + j0 + lb_n] : 0.f;
            }
        }
#pragma unroll
        for (int kk = 0; kk < 16; ++kk) {
            float4 a0 = *(const float4*)&As[kk][ty * 4];
            float4 a1 = *(const float4*)&As[kk][ty * 4 + 64];
            float4 b0 = *(const float4*)&Bs[kk][tx * 4];
            float4 b1 = *(const float4*)&Bs[kk][tx * 4 + 64];
            float av[8] = {a0.x, a0.y, a0.z, a0.w, a1.x, a1.y, a1.z, a1.w};
            float bv[8] = {b0.x, b0.y, b0.z, b0.w, b1.x, b1.y, b1.z, b1.w};
#pragma unroll
            for (int ii = 0; ii < 8; ++ii)
#pragma unroll
                for (int jj = 0; jj < 8; ++jj)
                    acc[ii][jj] = fmaf(av[ii], bv[jj], acc[ii][jj]);
        }
        __syncthreads();
    }

#pragma unroll
    for (int v = 0; v < 2; ++v) {
#pragma unroll
        for (int rr = 0; rr < 4; ++rr) {
            int i = i0 + ty * 4 + 64 * v + rr;
            int ii = v * 4 + rr;
#pragma unroll
            for (int u = 0; u < 2; ++u) {
#pragma unroll
                for (int cc = 0; cc < 4; ++cc) {
                    int j = j0 + tx * 4 + 64 * u + cc;
                    if (j < N) {
                        float val = acc[ii][u * 4 + cc] + bias[j];
                        if (RELU) val = fmaxf(val, 0.f);
                        Cm[(long)i * N + j] = val;
                    }
                }
            }
        }
    }
}

// ---------------- fp32 GEMM 64x64 (layers 2-4), BK=32 prefetch ----------------
template<int RELU>
__global__ __launch_bounds__(256) void gemm_kernel(const float* __restrict__ A, const float* __restrict__ B,
                                                   const float* __restrict__ bias, float* __restrict__ Cm,
                                                   int K, int N) {
    __shared__ float As[32][68];
    __shared__ float Bs[32][68];
    const int tid = threadIdx.x;
    const int i0 = blockIdx.y * 64, j0 = blockIdx.x * 64;
    const int ty = tid >> 4, tx = tid & 15;
    const int la_c = tid & 31, la_r = tid >> 5;
    const int lb_n = tid & 63, lb_k = tid >> 6;

    float ra[8], rb[8];
    float acc[4][4];
#pragma unroll
    for (int a = 0; a < 4; ++a)
#pragma unroll
        for (int b = 0; b < 4; ++b) acc[a][b] = 0.f;

    {
        const bool bn = (j0 + lb_n < N);
#pragma unroll
        for (int q = 0; q < 8; ++q) {
            int r = la_r + 8 * q;
            ra[q] = (la_c < K) ? A[(long)(i0 + r) * K + la_c] : 0.f;
            int kk = lb_k + 4 * q;
            rb[q] = (kk < K && bn) ? B[(long)kk * N + j0 + lb_n] : 0.f;
        }
    }

    for (int k0 = 0; k0 < K; k0 += 32) {
#pragma unroll
        for (int q = 0; q < 8; ++q) {
            As[la_c][la_r + 8 * q] = ra[q];
            Bs[lb_k + 4 * q][lb_n] = rb[q];
        }
        __syncthreads();
        if (k0 + 32 < K) {
            const bool bn = (j0 + lb_n < N);
#pragma unroll
            for (int q = 0; q < 8; ++q) {
                int r = la_r + 8 * q;
                ra[q] = (k0 + 32 + la_c < K) ? A[(long)(i0 + r) * K + k0 + 32 + la_c] : 0.f;
                int kk = k0 + 32 + lb_k + 4 * q;
                rb[q] = (kk < K && bn) ? B[(long)kk * N + j0 + lb_n] : 0.f;
            }
        }
#pragma unroll
        for (int kk = 0; kk < 32; ++kk) {
            float4 a4 = *(const float4*)&As[kk][ty * 4];
            float4 b4 = *(const float4*)&Bs[kk][tx * 4];
            float av[4] = {a4.x, a4.y, a4.z, a4.w};
            float bv[4] = {b4.x, b4.y, b4.z, b4.w};
#pragma unroll
            for (int ii = 0; ii < 4; ++ii)
#pragma unroll
                for (int jj = 0; jj < 4; ++jj)
                    acc[ii][jj] = fmaf(av[ii], bv[jj], acc[ii][jj]);
        }
        __syncthreads();
    }

#pragma unroll
    for (int ii = 0; ii < 4; ++ii) {
        int i = i0 + ty * 4 + ii;
#pragma unroll
        for (int jj = 0; jj < 4; ++jj) {
            int j = j0 + tx * 4 + jj;
            if (j < N) {
                float v = acc[ii][jj] + bias[j];
                if (RELU) v = fmaxf(v, 0.f);
                Cm[(long)i * N + j] = v;
            }
        }
    }
}

// ---------------- log_softmax over 40 cols, wave per row, in place ----------------
__global__ void logsoftmax_kernel(float* __restrict__ out) {
    const int lane = threadIdx.x & 63;
    const int wid = threadIdx.x >> 6;
    const int row = blockIdx.x * 4 + wid;
    float* o = out + (long)row * 40;
    float v = (lane < 40) ? o[lane] : -INFINITY;
    float m = v;
#pragma unroll
    for (int off = 1; off < 64; off <<= 1) m = fmaxf(m, __shfl_xor(m, off));
    float e = (lane < 40) ? expf(v - m) : 0.f;
    float s = e;
#pragma unroll
    for (int off = 1; off < 64; off <<= 1) s += __shfl_xor(s, off);
    float r = (v - m) - logf(s);
    if (lane < 40) o[lane] = r;
}

extern "C" void kernel_launch(void* const* d_in, const int* in_sizes, int n_in,
                              void* d_out, int out_size, void* d_ws, size_t ws_size,
                              hipStream_t stream) {
    (void)in_sizes; (void)n_in; (void)out_size;
    const float* x     = (const float*)d_in[0];
    const float* w1    = (const float*)d_in[1];
    const float* w2    = (const float*)d_in[2];
    const float* w3    = (const float*)d_in[3];
    const float* lin1w = (const float*)d_in[4];
    const float* lin1b = (const float*)d_in[5];
    const float* wa    = (const float*)d_in[6];
    const float* ba    = (const float*)d_in[7];
    const float* wb    = (const float*)d_in[8];
    const float* bb    = (const float*)d_in[9];
    const float* wo    = (const float*)d_in[10];
    const float* bo    = (const float*)d_in[11];
    float* outp = (float*)d_out;

    // ---- ws_size-adaptive layout ----
    char* ws = (char*)d_ws;
    size_t off = 0;
    auto take = [&](size_t bytes) { char* p = ws + off; off += (bytes + 255) & ~(size_t)255; return p; };
    float* x2  = (float*)take((size_t)NPTS * 4);
    int*   idx = (int*)  take((size_t)NPTS * KNN * 4);
    float* h0  = (float*)take((size_t)NPTS * 420 * 4);
    float* sx0 = (float*)take((size_t)NPTS * 4);
    float* sx1 = (float*)take((size_t)NPTS * 4);
    float* sx2 = (float*)take((size_t)NPTS * 4);
    float* XT  = (float*)take((size_t)NPTS * 120 * 4);   // transposed slab (max C=120)
    size_t rest = (ws_size > off) ? (ws_size - off) : 0;
    char*  scratch = ws + off;

    int cr = (int)(rest / ((size_t)NPTS * 4));   // fp32 dist chunk rows
    if (cr > 4096) cr = 4096;                    // 128 MB chunk: topk re-read stays L3-resident
    cr &= ~127;
    if (cr < 128) cr = 128;
    float* dist = (float*)scratch;

    int mr = (int)(rest / 5632);                 // fp32 MLP chunk rows
    if (mr > NPTS) mr = NPTS;
    mr &= ~127;
    if (mr < 128) mr = 128;

    dim3 b256(256);
    dim3 b512(NT);
    dim3 grow(NPTS);

    // ---- stage 1: fused knn(x, C=3) -> erode -> x1 = h0[:, 0:60]
    rowsq_np_kernel<3><<<dim3(32), b256, 0, stream>>>(x, 3, x2);
    soa3_kernel<<<dim3(32), b256, 0, stream>>>(x, sx0, sx1, sx2);
    knn3_fused_kernel<<<grow, b512, 0, stream>>>(sx0, sx1, sx2, x2, idx);
    erode_kernel<20, 3><<<grow, dim3(64), 0, stream>>>(x, 3, idx, w1, h0 + 0, 420);

    // ---- stage 2: knn(x1, C=60) -> erode -> x2f = h0[:, 60:180]
    rowsq_np_kernel<60><<<dim3(32), b256, 0, stream>>>(h0, 420, x2);
    transpose_kernel<<<dim3(NPTS / 32, 2), b256, 0, stream>>>(h0, 420, 60, XT);
    for (int r0 = 0; r0 < NPTS; r0 += cr) {
        int rows = (NPTS - r0 < cr) ? (NPTS - r0) : cr;
        dist128_kernel<<<dim3(64, rows / 128), b256, 0, stream>>>(XT, 60, x2, dist, r0);
        topk_kernel<<<dim3(rows), b512, 0, stream>>>(dist, idx, r0);
    }
    erode_kernel<2, 60><<<grow, dim3(128), 0, stream>>>(h0, 420, idx, w2, h0 + 60, 420);

    // ---- stage 3: knn(x2f, C=120) -> erode -> x3 = h0[:, 180:420]
    rowsq_np_kernel<120><<<dim3(32), b256, 0, stream>>>(h0 + 60, 420, x2);
    transpose_kernel<<<dim3(NPTS / 32, 4), b256, 0, stream>>>(h0 + 60, 420, 120, XT);
    for (int r0 = 0; r0 < NPTS; r0 += cr) {
        int rows = (NPTS - r0 < cr) ? (NPTS - r0) : cr;
        dist128_kernel<<<dim3(64, rows / 128), b256, 0, stream>>>(XT, 120, x2, dist, r0);
        topk_kernel<<<dim3(rows), b512, 0, stream>>>(dist, idx, r0);
    }
    erode_kernel<2, 120><<<grow, dim3(256), 0, stream>>>(h0 + 60, 420, idx, w3, h0 + 180, 420);

    // ---- MLP (row-chunked; h1|h2|h3 live in scratch)
    for (int r0 = 0; r0 < NPTS; r0 += mr) {
        int rows = (NPTS - r0 < mr) ? (NPTS - r0) : mr;
        float* h1c = (float*)scratch;
        float* h2c = h1c + (size_t)mr * 1024;
        float* h3c = h2c + (size_t)mr * 256;
        gemm128_kernel<1><<<dim3(8, rows / 128), b256, 0, stream>>>(h0 + (long)r0 * 420, lin1w, lin1b, h1c, 420, 1024);
        gemm_kernel<1><<<dim3(4, rows / 64), b256, 0, stream>>>(h1c, wa, ba, h2c, 1024, 256);
        gemm_kernel<1><<<dim3(2, rows / 64), b256, 0, stream>>>(h2c, wb, bb, h3c, 256, 128);
        gemm_kernel<0><<<dim3(1, rows / 64), b256, 0, stream>>>(h3c, wo, bo, outp + (long)r0 * 40, 128, 40);
        logsoftmax_kernel<<<dim3(rows / 4), b256, 0, stream>>>(outp + (long)r0 * 40);
    }
}